// Round 1
// baseline (2634.161 us; speedup 1.0000x reference)
//
#include <hip/hip_runtime.h>
#include <math.h>

#define B 4
#define L 2048
#define E 1024
#define H 16
#define HD 64
#define MROWS (B*L)      // 8192
#define E3 (3*E)         // 3072

// ------------------------------------------------------------------
// C[M,N] = A[M,K] @ Bw[N,K]^T + bias[N]   (all fp32, row-major)
// 64x64 tile, BK=16, 256 threads, 4x4 microtile per thread.
// ------------------------------------------------------------------
__global__ __launch_bounds__(256) void gemm_bt(
        const float* __restrict__ A, const float* __restrict__ Bw,
        const float* __restrict__ bias, float* __restrict__ C,
        int Mdim, int Ndim, int Kdim)
{
    __shared__ float As[16][68];   // [k][m], stride 68 keeps b128 align + 2-way-max banks
    __shared__ float Bs[16][68];   // [k][n]

    const int tid = threadIdx.x;
    const int tx = tid & 15, ty = tid >> 4;
    const int m0 = blockIdx.y * 64, n0 = blockIdx.x * 64;

    const int lr = tid >> 2;          // 0..63 row within tile
    const int lk = (tid & 3) << 2;    // 0,4,8,12
    const float* Arow = A + (size_t)(m0 + lr) * Kdim + lk;
    const float* Brow = Bw + (size_t)(n0 + lr) * Kdim + lk;

    float acc[4][4] = {};

    for (int k0 = 0; k0 < Kdim; k0 += 16) {
        float4 av = *(const float4*)(Arow + k0);
        float4 bv = *(const float4*)(Brow + k0);
        __syncthreads();   // previous iteration's LDS reads must be done
        As[lk + 0][lr] = av.x; As[lk + 1][lr] = av.y;
        As[lk + 2][lr] = av.z; As[lk + 3][lr] = av.w;
        Bs[lk + 0][lr] = bv.x; Bs[lk + 1][lr] = bv.y;
        Bs[lk + 2][lr] = bv.z; Bs[lk + 3][lr] = bv.w;
        __syncthreads();
#pragma unroll
        for (int kk = 0; kk < 16; ++kk) {
            float4 a4 = *(const float4*)&As[kk][ty * 4];
            float4 b4 = *(const float4*)&Bs[kk][tx * 4];
            acc[0][0] += a4.x * b4.x; acc[0][1] += a4.x * b4.y;
            acc[0][2] += a4.x * b4.z; acc[0][3] += a4.x * b4.w;
            acc[1][0] += a4.y * b4.x; acc[1][1] += a4.y * b4.y;
            acc[1][2] += a4.y * b4.z; acc[1][3] += a4.y * b4.w;
            acc[2][0] += a4.z * b4.x; acc[2][1] += a4.z * b4.y;
            acc[2][2] += a4.z * b4.z; acc[2][3] += a4.z * b4.w;
            acc[3][0] += a4.w * b4.x; acc[3][1] += a4.w * b4.y;
            acc[3][2] += a4.w * b4.z; acc[3][3] += a4.w * b4.w;
        }
    }

    float4 bb = *(const float4*)&bias[n0 + tx * 4];
#pragma unroll
    for (int i = 0; i < 4; ++i) {
        float4 ov;
        ov.x = acc[i][0] + bb.x; ov.y = acc[i][1] + bb.y;
        ov.z = acc[i][2] + bb.z; ov.w = acc[i][3] + bb.w;
        *(float4*)&C[(size_t)(m0 + ty * 4 + i) * Ndim + n0 + tx * 4] = ov;
    }
}

// ------------------------------------------------------------------
// Fused flash attention with RoPE applied at K/Q tile load.
// qkv layout: [B, L, 3E]  (q | k | v per row)
// attn out  : [B, L, E]   (head-interleaved, ready for out-proj)
// Block: 256 threads, one (b,h) x 64-row Q tile. 32 K-tiles of 64.
// ------------------------------------------------------------------
__global__ __launch_bounds__(256) void flash_rope(
        const float* __restrict__ qkv, const float* __restrict__ cosT,
        const float* __restrict__ sinT, float* __restrict__ attn)
{
    __shared__ float Qs[64][68];
    __shared__ float Ks[64][68];
    __shared__ float Vs[64][68];
    __shared__ float Ps[64][68];

    const int tid = threadIdx.x;
    const int tx = tid & 15, ty = tid >> 4;
    const int bh = blockIdx.x;
    const int b = bh / H, h = bh % H;
    const int q0 = blockIdx.y * 64;
    const float scale = 0.125f;   // 1/sqrt(64)

    // ---- load Q tile, apply RoPE + scale ----
#pragma unroll
    for (int it = 0; it < 8; ++it) {
        int p = tid + 256 * it;          // 0..2047 : 64 rows x 32 pairs
        int r = p >> 5, d = p & 31;
        int l = q0 + r;
        size_t base = ((size_t)(b * L + l)) * E3 + h * HD;
        float q1 = qkv[base + d], q2 = qkv[base + d + 32];
        float c = cosT[l * 32 + d], s = sinT[l * 32 + d];
        Qs[r][d]      = (q1 * c - q2 * s) * scale;
        Qs[r][d + 32] = (q1 * s + q2 * c) * scale;
    }

    float m_i[4], l_i[4];
    float o[4][4] = {};
#pragma unroll
    for (int i = 0; i < 4; ++i) { m_i[i] = -INFINITY; l_i[i] = 0.f; }

    for (int k0 = 0; k0 < L; k0 += 64) {
        __syncthreads();   // prev-iter LDS readers done (also covers Q staging, iter 0)
        // ---- stage K tile (RoPE) ----
#pragma unroll
        for (int it = 0; it < 8; ++it) {
            int p = tid + 256 * it;
            int r = p >> 5, d = p & 31;
            int l = k0 + r;
            size_t base = ((size_t)(b * L + l)) * E3 + E + h * HD;
            float k1 = qkv[base + d], k2 = qkv[base + d + 32];
            float c = cosT[l * 32 + d], s = sinT[l * 32 + d];
            Ks[r][d]      = k1 * c - k2 * s;
            Ks[r][d + 32] = k1 * s + k2 * c;
        }
        // ---- stage V tile ----
#pragma unroll
        for (int it = 0; it < 4; ++it) {
            int p = tid + 256 * it;      // 0..1023 : 64 rows x 16 float4
            int r = p >> 4, f = p & 15;
            size_t base = ((size_t)(b * L + k0 + r)) * E3 + 2 * E + h * HD;
            *(float4*)&Vs[r][f * 4] = *(const float4*)(qkv + base + f * 4);
        }
        __syncthreads();

        // ---- S = Qs . Ks^T : rows ty*4+i, key-cols tx*4+j ----
        float s[4][4] = {};
#pragma unroll
        for (int d4 = 0; d4 < 16; ++d4) {
            float4 qv[4];
#pragma unroll
            for (int i = 0; i < 4; ++i) qv[i] = *(const float4*)&Qs[ty * 4 + i][d4 * 4];
#pragma unroll
            for (int j = 0; j < 4; ++j) {
                float4 kv = *(const float4*)&Ks[tx * 4 + j][d4 * 4];
#pragma unroll
                for (int i = 0; i < 4; ++i)
                    s[i][j] += qv[i].x * kv.x + qv[i].y * kv.y
                             + qv[i].z * kv.z + qv[i].w * kv.w;
            }
        }

        // ---- online softmax (rows are groups of 16 contiguous lanes) ----
#pragma unroll
        for (int i = 0; i < 4; ++i) {
            float rmax = fmaxf(fmaxf(s[i][0], s[i][1]), fmaxf(s[i][2], s[i][3]));
#pragma unroll
            for (int off = 1; off < 16; off <<= 1)
                rmax = fmaxf(rmax, __shfl_xor(rmax, off, 16));
            float mnew = fmaxf(m_i[i], rmax);
            float alpha = __expf(m_i[i] - mnew);   // 0 on first tile
            float rsum = 0.f;
#pragma unroll
            for (int j = 0; j < 4; ++j) {
                float pv = __expf(s[i][j] - mnew);
                Ps[ty * 4 + i][tx * 4 + j] = pv;
                rsum += pv;
            }
#pragma unroll
            for (int off = 1; off < 16; off <<= 1)
                rsum += __shfl_xor(rsum, off, 16);
            l_i[i] = l_i[i] * alpha + rsum;
            m_i[i] = mnew;
#pragma unroll
            for (int j = 0; j < 4; ++j) o[i][j] *= alpha;
        }
        __syncthreads();   // Ps visible to all lanes

        // ---- O += P . V : rows ty*4+i, d-cols tx*4+j ----
#pragma unroll
        for (int c4 = 0; c4 < 16; ++c4) {
            float p[4][4];
#pragma unroll
            for (int i = 0; i < 4; ++i)
                *(float4*)&p[i][0] = *(const float4*)&Ps[ty * 4 + i][c4 * 4];
#pragma unroll
            for (int cc = 0; cc < 4; ++cc) {
                float4 vv = *(const float4*)&Vs[c4 * 4 + cc][tx * 4];
#pragma unroll
                for (int i = 0; i < 4; ++i) {
                    o[i][0] += p[i][cc] * vv.x;
                    o[i][1] += p[i][cc] * vv.y;
                    o[i][2] += p[i][cc] * vv.z;
                    o[i][3] += p[i][cc] * vv.w;
                }
            }
        }
    }

    // ---- epilogue: divide by l, write [B,L,E] ----
#pragma unroll
    for (int i = 0; i < 4; ++i) {
        float inv = 1.f / l_i[i];
        float4 ov;
        ov.x = o[i][0] * inv; ov.y = o[i][1] * inv;
        ov.z = o[i][2] * inv; ov.w = o[i][3] * inv;
        int l = q0 + ty * 4 + i;
        *(float4*)&attn[((size_t)(b * L + l)) * E + h * HD + tx * 4] = ov;
    }
}

extern "C" void kernel_launch(void* const* d_in, const int* in_sizes, int n_in,
                              void* d_out, int out_size, void* d_ws, size_t ws_size,
                              hipStream_t stream) {
    const float* x    = (const float*)d_in[0];   // [B,L,E]
    const float* cosT = (const float*)d_in[1];   // [1,1,L,32]
    const float* sinT = (const float*)d_in[2];   // [1,1,L,32]
    const float* Wqkv = (const float*)d_in[3];   // [3E,E]
    const float* bqkv = (const float*)d_in[4];   // [3E]
    const float* Wout = (const float*)d_in[5];   // [E,E]
    const float* bout = (const float*)d_in[6];   // [E]
    float* out = (float*)d_out;                  // [B,L,E]

    float* qkv  = (float*)d_ws;                          // MROWS*3E = 96 MB
    float* attn = (float*)d_ws + (size_t)MROWS * E3;     // MROWS*E  = 32 MB

    // 1) qkv = x @ Wqkv^T + bqkv
    gemm_bt<<<dim3(E3 / 64, MROWS / 64), 256, 0, stream>>>(
        x, Wqkv, bqkv, qkv, MROWS, E3, E);

    // 2) fused rope + flash attention -> attn [B,L,E]
    flash_rope<<<dim3(B * H, L / 64), 256, 0, stream>>>(qkv, cosT, sinT, attn);

    // 3) out = attn @ Wout^T + bout
    gemm_bt<<<dim3(E / 64, MROWS / 64), 256, 0, stream>>>(
        attn, Wout, bout, out, MROWS, E, E);
}

// Round 2
// 1448.968 us; speedup vs baseline: 1.8180x; 1.8180x over previous
//
#include <hip/hip_runtime.h>
#include <math.h>

#define B 4
#define L 2048
#define E 1024
#define H 16
#define HD 64
#define MROWS (B*L)      // 8192
#define E3 (3*E)         // 3072

using bf16x8  = __attribute__((ext_vector_type(8))) short;
using floatx4 = __attribute__((ext_vector_type(4))) float;

__device__ inline ushort f2bf(float x) {
    uint u = __float_as_uint(x);
    u += 0x7FFF + ((u >> 16) & 1);     // RNE
    return (ushort)(u >> 16);
}
__device__ inline uint pack2(float a, float b) {
    return (uint)f2bf(a) | ((uint)f2bf(b) << 16);
}

// ------------------------------------------------------------------
// C[M,N] = A[M,K] @ Bw[N,K]^T + bias[N]   (fp32) — unchanged from R1
// ------------------------------------------------------------------
__global__ __launch_bounds__(256) void gemm_bt(
        const float* __restrict__ A, const float* __restrict__ Bw,
        const float* __restrict__ bias, float* __restrict__ C,
        int Mdim, int Ndim, int Kdim)
{
    __shared__ float As[16][68];
    __shared__ float Bs[16][68];

    const int tid = threadIdx.x;
    const int tx = tid & 15, ty = tid >> 4;
    const int m0 = blockIdx.y * 64, n0 = blockIdx.x * 64;

    const int lr = tid >> 2;
    const int lk = (tid & 3) << 2;
    const float* Arow = A + (size_t)(m0 + lr) * Kdim + lk;
    const float* Brow = Bw + (size_t)(n0 + lr) * Kdim + lk;

    float acc[4][4] = {};

    for (int k0 = 0; k0 < Kdim; k0 += 16) {
        float4 av = *(const float4*)(Arow + k0);
        float4 bv = *(const float4*)(Brow + k0);
        __syncthreads();
        As[lk + 0][lr] = av.x; As[lk + 1][lr] = av.y;
        As[lk + 2][lr] = av.z; As[lk + 3][lr] = av.w;
        Bs[lk + 0][lr] = bv.x; Bs[lk + 1][lr] = bv.y;
        Bs[lk + 2][lr] = bv.z; Bs[lk + 3][lr] = bv.w;
        __syncthreads();
#pragma unroll
        for (int kk = 0; kk < 16; ++kk) {
            float4 a4 = *(const float4*)&As[kk][ty * 4];
            float4 b4 = *(const float4*)&Bs[kk][tx * 4];
            acc[0][0] += a4.x * b4.x; acc[0][1] += a4.x * b4.y;
            acc[0][2] += a4.x * b4.z; acc[0][3] += a4.x * b4.w;
            acc[1][0] += a4.y * b4.x; acc[1][1] += a4.y * b4.y;
            acc[1][2] += a4.y * b4.z; acc[1][3] += a4.y * b4.w;
            acc[2][0] += a4.z * b4.x; acc[2][1] += a4.z * b4.y;
            acc[2][2] += a4.z * b4.z; acc[2][3] += a4.z * b4.w;
            acc[3][0] += a4.w * b4.x; acc[3][1] += a4.w * b4.y;
            acc[3][2] += a4.w * b4.z; acc[3][3] += a4.w * b4.w;
        }
    }

    float4 bb = *(const float4*)&bias[n0 + tx * 4];
#pragma unroll
    for (int i = 0; i < 4; ++i) {
        float4 ov;
        ov.x = acc[i][0] + bb.x; ov.y = acc[i][1] + bb.y;
        ov.z = acc[i][2] + bb.z; ov.w = acc[i][3] + bb.w;
        *(float4*)&C[(size_t)(m0 + ty * 4 + i) * Ndim + n0 + tx * 4] = ov;
    }
}

// ------------------------------------------------------------------
// MFMA flash attention, RoPE fused at Q/K staging (bf16 in, fp32 acc).
// Block = 256 thr (4 waves); wave w owns Q rows [16w,16w+16) of a 64-row
// Q tile for one (b,h). LDS rows stride 72 bf16 = 144 B (16B-aligned,
// frag reads bank-uniform).
// ------------------------------------------------------------------
#define LSTR 72

__global__ __launch_bounds__(256) void flash_mfma(
        const float* __restrict__ qkv, const float* __restrict__ cosT,
        const float* __restrict__ sinT, float* __restrict__ attn)
{
    __shared__ ushort Qs[64 * LSTR];
    __shared__ ushort Ks[64 * LSTR];
    __shared__ ushort Vt[64 * LSTR];   // [d][kpos] (transposed)
    __shared__ ushort Ps[64 * LSTR];   // per-wave 16-row regions

    const int tid  = threadIdx.x;
    const int w    = tid >> 6;
    const int lane = tid & 63;
    const int g    = lane >> 4;       // quad
    const int c    = lane & 15;
    const int b    = blockIdx.x >> 4; // H = 16
    const int h    = blockIdx.x & 15;
    const int q0   = blockIdx.y * 64;

    // ---- stage Q tile: rope + 1/8 scale -> bf16 ----
#pragma unroll
    for (int it = 0; it < 4; ++it) {
        int p = tid + 256 * it;          // 64 rows x 16 d-pairs
        int r = p >> 4, d2 = (p & 15) * 2;
        int l = q0 + r;
        const float* base = qkv + (size_t)(b * L + l) * E3 + h * HD;
        float2 x1 = *(const float2*)(base + d2);
        float2 x2 = *(const float2*)(base + d2 + 32);
        float2 cc = *(const float2*)(cosT + l * 32 + d2);
        float2 ss = *(const float2*)(sinT + l * 32 + d2);
        *(uint*)&Qs[r * LSTR + d2]      = pack2((x1.x*cc.x - x2.x*ss.x)*0.125f,
                                                (x1.y*cc.y - x2.y*ss.y)*0.125f);
        *(uint*)&Qs[r * LSTR + d2 + 32] = pack2((x1.x*ss.x + x2.x*cc.x)*0.125f,
                                                (x1.y*ss.y + x2.y*cc.y)*0.125f);
    }
    __syncthreads();

    // A-frags of Q, kept in regs for the whole loop (A: m=lane&15, k=g*8+j)
    bf16x8 aq0 = *(const bf16x8*)&Qs[(16 * w + c) * LSTR + g * 8];
    bf16x8 aq1 = *(const bf16x8*)&Qs[(16 * w + c) * LSTR + 32 + g * 8];

    float m_i[4], l_i[4];
    floatx4 o[4];
#pragma unroll
    for (int i = 0; i < 4; ++i) { m_i[i] = -INFINITY; l_i[i] = 0.f; }
#pragma unroll
    for (int js = 0; js < 4; ++js) o[js] = (floatx4){0.f, 0.f, 0.f, 0.f};

    for (int k0 = 0; k0 < L; k0 += 64) {
        __syncthreads();   // prior iter's Ks/Vt readers done

        // ---- stage K tile (rope) ----
#pragma unroll
        for (int it = 0; it < 4; ++it) {
            int p = tid + 256 * it;
            int r = p >> 4, d2 = (p & 15) * 2;
            int l = k0 + r;
            const float* base = qkv + (size_t)(b * L + l) * E3 + E + h * HD;
            float2 x1 = *(const float2*)(base + d2);
            float2 x2 = *(const float2*)(base + d2 + 32);
            float2 cc = *(const float2*)(cosT + l * 32 + d2);
            float2 ss = *(const float2*)(sinT + l * 32 + d2);
            *(uint*)&Ks[r * LSTR + d2]      = pack2(x1.x*cc.x - x2.x*ss.x,
                                                    x1.y*cc.y - x2.y*ss.y);
            *(uint*)&Ks[r * LSTR + d2 + 32] = pack2(x1.x*ss.x + x2.x*cc.x,
                                                    x1.y*ss.y + x2.y*cc.y);
        }
        // ---- stage V transposed: Vt[d][kpos], lanes spread over d&7 x kp
        //      so write banks = 4*(d&7) + (kp>>1) -> <=2-way ----
#pragma unroll
        for (int it = 0; it < 8; ++it) {
            int p  = tid + 256 * it;
            int d  = (p & 7) | (((p >> 6) & 7) << 3);
            int rp = ((p >> 3) & 7) | ((p >> 9) << 3);
            int r  = rp * 2;
            const float* base = qkv + (size_t)(b * L + k0 + r) * E3 + 2 * E + h * HD + d;
            float v0 = base[0];
            float v1 = base[E3];
            *(uint*)&Vt[d * LSTR + r] = pack2(v0, v1);
        }
        __syncthreads();

        // ---- S = Q K^T (B: n=lane&15, k=g*8+j -> read K[n][k..k+8]) ----
        floatx4 s[4];
#pragma unroll
        for (int js = 0; js < 4; ++js) {
            floatx4 acc = (floatx4){0.f, 0.f, 0.f, 0.f};
            acc = __builtin_amdgcn_mfma_f32_16x16x32_bf16(aq0,
                    *(const bf16x8*)&Ks[(16 * js + c) * LSTR + g * 8], acc, 0, 0, 0);
            acc = __builtin_amdgcn_mfma_f32_16x16x32_bf16(aq1,
                    *(const bf16x8*)&Ks[(16 * js + c) * LSTR + 32 + g * 8], acc, 0, 0, 0);
            s[js] = acc;
        }

        // ---- online softmax; C-layout row = 4g+i, col = 16js+c ----
        float alpha[4];
#pragma unroll
        for (int i = 0; i < 4; ++i) {
            float rm = fmaxf(fmaxf(s[0][i], s[1][i]), fmaxf(s[2][i], s[3][i]));
#pragma unroll
            for (int off = 1; off < 16; off <<= 1)
                rm = fmaxf(rm, __shfl_xor(rm, off, 16));
            float mn = fmaxf(m_i[i], rm);
            float al = __expf(m_i[i] - mn);
            float rs = 0.f;
#pragma unroll
            for (int js = 0; js < 4; ++js) {
                float pv = __expf(s[js][i] - mn);
                Ps[(16 * w + 4 * g + i) * LSTR + 16 * js + c] = f2bf(pv);
                rs += pv;
            }
#pragma unroll
            for (int off = 1; off < 16; off <<= 1)
                rs += __shfl_xor(rs, off, 16);
            l_i[i] = l_i[i] * al + rs;
            m_i[i] = mn;
            alpha[i] = al;
        }
#pragma unroll
        for (int js = 0; js < 4; ++js)
#pragma unroll
            for (int i = 0; i < 4; ++i)
                o[js][i] *= alpha[i];

        // wave-private P round-trip: order writes before reads
        asm volatile("s_waitcnt lgkmcnt(0)" ::: "memory");

        bf16x8 ap0 = *(const bf16x8*)&Ps[(16 * w + c) * LSTR + g * 8];
        bf16x8 ap1 = *(const bf16x8*)&Ps[(16 * w + c) * LSTR + 32 + g * 8];

        // ---- O += P V (B from Vt: n=dcol=16js+c row, k contiguous) ----
#pragma unroll
        for (int js = 0; js < 4; ++js) {
            o[js] = __builtin_amdgcn_mfma_f32_16x16x32_bf16(ap0,
                      *(const bf16x8*)&Vt[(16 * js + c) * LSTR + g * 8], o[js], 0, 0, 0);
            o[js] = __builtin_amdgcn_mfma_f32_16x16x32_bf16(ap1,
                      *(const bf16x8*)&Vt[(16 * js + c) * LSTR + 32 + g * 8], o[js], 0, 0, 0);
        }
    }

    // ---- epilogue ----
#pragma unroll
    for (int i = 0; i < 4; ++i) {
        float inv = 1.f / l_i[i];
        int row = q0 + 16 * w + 4 * g + i;
        float* dst = attn + (size_t)(b * L + row) * E + h * HD + c;
        dst[0]  = o[0][i] * inv;
        dst[16] = o[1][i] * inv;
        dst[32] = o[2][i] * inv;
        dst[48] = o[3][i] * inv;
    }
}

extern "C" void kernel_launch(void* const* d_in, const int* in_sizes, int n_in,
                              void* d_out, int out_size, void* d_ws, size_t ws_size,
                              hipStream_t stream) {
    const float* x    = (const float*)d_in[0];
    const float* cosT = (const float*)d_in[1];
    const float* sinT = (const float*)d_in[2];
    const float* Wqkv = (const float*)d_in[3];
    const float* bqkv = (const float*)d_in[4];
    const float* Wout = (const float*)d_in[5];
    const float* bout = (const float*)d_in[6];
    float* out = (float*)d_out;

    float* qkv  = (float*)d_ws;                          // 96 MB
    float* attn = (float*)d_ws + (size_t)MROWS * E3;     // 32 MB

    gemm_bt<<<dim3(E3 / 64, MROWS / 64), 256, 0, stream>>>(
        x, Wqkv, bqkv, qkv, MROWS, E3, E);

    flash_mfma<<<dim3(B * H, L / 64), 256, 0, stream>>>(qkv, cosT, sinT, attn);

    gemm_bt<<<dim3(E / 64, MROWS / 64), 256, 0, stream>>>(
        attn, Wout, bout, out, MROWS, E, E);
}

// Round 3
// 558.754 us; speedup vs baseline: 4.7143x; 2.5932x over previous
//
#include <hip/hip_runtime.h>
#include <math.h>

#define B 4
#define L 2048
#define E 1024
#define H 16
#define HD 64
#define MROWS (B*L)      // 8192
#define E3 (3*E)         // 3072
#define LSTR 72

using bf16x8  = __attribute__((ext_vector_type(8))) short;
using floatx4 = __attribute__((ext_vector_type(4))) float;

__device__ inline ushort f2bf(float x) {
    uint u = __float_as_uint(x);
    u += 0x7FFF + ((u >> 16) & 1);     // RNE
    return (ushort)(u >> 16);
}
__device__ inline float bf2f(ushort h) { return __uint_as_float(((uint)h) << 16); }

__device__ inline void async16(const void* g, void* l) {
    __builtin_amdgcn_global_load_lds(
        (const __attribute__((address_space(1))) uint*)g,
        (__attribute__((address_space(3))) uint*)l, 16, 0, 0);
}

// ------------------------------------------------------------------
// fp32 -> bf16 hi/lo split (exact to ~2^-17 relative)
// ------------------------------------------------------------------
__global__ __launch_bounds__(256) void split_hl(const float* __restrict__ src,
        ushort* __restrict__ hi, ushort* __restrict__ lo, int n4)
{
    int i = blockIdx.x * 256 + threadIdx.x;
    if (i >= n4) return;
    float4 v = ((const float4*)src)[i];
    ushort4 hv, lv;
    hv.x = f2bf(v.x); lv.x = f2bf(v.x - bf2f(hv.x));
    hv.y = f2bf(v.y); lv.y = f2bf(v.y - bf2f(hv.y));
    hv.z = f2bf(v.z); lv.z = f2bf(v.z - bf2f(hv.z));
    hv.w = f2bf(v.w); lv.w = f2bf(v.w - bf2f(hv.w));
    ((ushort4*)hi)[i] = hv;
    ((ushort4*)lo)[i] = lv;
}

// ------------------------------------------------------------------
// Split-bf16 3-pass MFMA GEMM: C = (Ah+Al)@(Bh+Bl)^T + bias (drop lo*lo).
// 128x128 tile, BK=32, 256 thr = 4 waves of 64x64. global_load_lds w=16,
// XOR-swizzled LDS (slot j ^ ((row>>1)&3)) -> 2-way max bank aliasing.
// MODE 1: epilogue = bias + RoPE + scale, writes q,k [B,H,L,HD] bf16 and
//         v transposed [B,H,HD,L] bf16.
// MODE 2: epilogue = bias, fp32 row-major out.
// ------------------------------------------------------------------
template<int MODE>
__global__ __launch_bounds__(256) void gemm_split(
        const ushort* __restrict__ Ah, const ushort* __restrict__ Al,
        const ushort* __restrict__ Bh, const ushort* __restrict__ Bl,
        const float* __restrict__ bias, float* __restrict__ Cf,
        ushort* __restrict__ qh, ushort* __restrict__ kh, ushort* __restrict__ vT,
        const float* __restrict__ cosT, const float* __restrict__ sinT,
        int Ndim, int Kdim)
{
    __shared__ ushort lds[16384];   // Ah | Al | Bh | Bl tiles, 4096 ushorts each

    const int tid = threadIdx.x;
    const int w = tid >> 6, lane = tid & 63;
    const int g = lane >> 4, c = lane & 15;
    const int m0 = blockIdx.y * 128, n0 = blockIdx.x * 128;
    const int wm = w & 1, wn = w >> 1;

    // wave w stages tile w; lane covers row rl0 (per 16-row issue), slot lane&3
    const int rl0 = lane >> 2;
    const int jsw = (lane & 3) ^ ((lane >> 3) & 3);   // swizzled source k-group
    const ushort* gbase =
        (w == 0) ? Ah + (size_t)m0 * Kdim :
        (w == 1) ? Al + (size_t)m0 * Kdim :
        (w == 2) ? Bh + (size_t)n0 * Kdim :
                   Bl + (size_t)n0 * Kdim;
    const ushort* lanesrc = gbase + (size_t)rl0 * Kdim + jsw * 8;
    ushort* ldst = &lds[w * 4096];

    floatx4 acc[4][4];
#pragma unroll
    for (int a = 0; a < 4; ++a)
#pragma unroll
        for (int bq = 0; bq < 4; ++bq) acc[a][bq] = (floatx4){0.f, 0.f, 0.f, 0.f};

    const int swz  = (g ^ ((c >> 1) & 3)) * 8;
    const int arow = wm * 2048 + c * 32;          // + mt*512 ; +4096 for lo tile
    const int brow = 8192 + wn * 2048 + c * 32;   // + nt*512 ; +4096 for lo tile

    for (int k0 = 0; k0 < Kdim; k0 += 32) {
        __syncthreads();
#pragma unroll
        for (int p = 0; p < 8; ++p)
            async16(lanesrc + (size_t)p * 16 * Kdim + k0, ldst + p * 512);
        asm volatile("s_waitcnt vmcnt(0)" ::: "memory");
        __syncthreads();

        bf16x8 ah[4], alo[4], bh[4], blo[4];
#pragma unroll
        for (int t = 0; t < 4; ++t) {
            ah[t]  = *(const bf16x8*)&lds[arow + t * 512 + swz];
            alo[t] = *(const bf16x8*)&lds[4096 + arow + t * 512 + swz];
            bh[t]  = *(const bf16x8*)&lds[brow + t * 512 + swz];
            blo[t] = *(const bf16x8*)&lds[4096 + brow + t * 512 + swz];
        }
#pragma unroll
        for (int mt = 0; mt < 4; ++mt)
#pragma unroll
            for (int nt = 0; nt < 4; ++nt) {
                acc[mt][nt] = __builtin_amdgcn_mfma_f32_16x16x32_bf16(ah[mt],  bh[nt],  acc[mt][nt], 0, 0, 0);
                acc[mt][nt] = __builtin_amdgcn_mfma_f32_16x16x32_bf16(alo[mt], bh[nt],  acc[mt][nt], 0, 0, 0);
                acc[mt][nt] = __builtin_amdgcn_mfma_f32_16x16x32_bf16(ah[mt],  blo[nt], acc[mt][nt], 0, 0, 0);
            }
    }

    // ---- epilogue; C/D: row = g*4+i, col = c (per 16x16 tile) ----
    const int colbase = n0 + wn * 64;   // 64-aligned -> one head / one section
#pragma unroll
    for (int mt = 0; mt < 4; ++mt) {
        const int rowb = m0 + wm * 64 + mt * 16 + g * 4;
        if constexpr (MODE == 2) {
#pragma unroll
            for (int i = 0; i < 4; ++i) {
                const int row = rowb + i;
#pragma unroll
                for (int nt = 0; nt < 4; ++nt) {
                    const int col = colbase + nt * 16 + c;
                    Cf[(size_t)row * Ndim + col] = acc[mt][nt][i] + bias[col];
                }
            }
        } else {
            const int sec = colbase >> 10;             // 0=q 1=k 2=v
            const int hg  = (colbase & 1023) >> 6;
#pragma unroll
            for (int i = 0; i < 4; ++i) {
                const int row = rowb + i;
                const int bb = row >> 11;
                const int l  = row & (L - 1);
                if (sec < 2) {
                    ushort* dst = (sec == 0 ? qh : kh) + ((size_t)(bb * H + hg) * L + l) * HD;
                    const float qs = (sec == 0) ? 0.125f : 1.0f;
#pragma unroll
                    for (int nt = 0; nt < 2; ++nt) {
                        const int d = nt * 16 + c;
                        float v1 = acc[mt][nt][i]     + bias[colbase + d];
                        float v2 = acc[mt][nt + 2][i] + bias[colbase + d + 32];
                        float cs = cosT[l * 32 + d], sn = sinT[l * 32 + d];
                        dst[d]      = f2bf((v1 * cs - v2 * sn) * qs);
                        dst[d + 32] = f2bf((v1 * sn + v2 * cs) * qs);
                    }
                } else {
#pragma unroll
                    for (int nt = 0; nt < 4; ++nt) {
                        const int d = nt * 16 + c;
                        float v = acc[mt][nt][i] + bias[colbase + d];
                        vT[((size_t)(bb * H + hg) * HD + d) * L + l] = f2bf(v);
                    }
                }
            }
        }
    }
}

// ------------------------------------------------------------------
// MFMA flash attention. q,k pre-roped/scaled bf16 [B,H,L,HD]; v bf16
// transposed [B,H,HD,L]. Writes attn as bf16 hi/lo [B,L,E].
// ------------------------------------------------------------------
__global__ __launch_bounds__(256) void flash_mfma(
        const ushort* __restrict__ qh, const ushort* __restrict__ kh,
        const ushort* __restrict__ vT,
        ushort* __restrict__ attn_h, ushort* __restrict__ attn_l)
{
    __shared__ ushort Qs[64 * LSTR];
    __shared__ ushort Ks[64 * LSTR];
    __shared__ ushort Vt[64 * LSTR];   // [d][kpos]
    __shared__ ushort Ps[64 * LSTR];   // per-wave 16-row regions

    const int tid  = threadIdx.x;
    const int w    = tid >> 6;
    const int lane = tid & 63;
    const int g    = lane >> 4;
    const int c    = lane & 15;
    const int b    = blockIdx.x >> 4;
    const int h    = blockIdx.x & 15;
    const int q0   = blockIdx.y * 64;

    const ushort* qhead = qh + (size_t)(b * H + h) * L * HD;
    const ushort* khead = kh + (size_t)(b * H + h) * L * HD;
    const ushort* vhead = vT + (size_t)(b * H + h) * HD * L;

    const int sr = tid >> 3, sj = (tid & 7) * 8;
    *(uint4*)&Qs[sr * LSTR + sj]        = *(const uint4*)&qhead[(size_t)(q0 + sr) * HD + sj];
    *(uint4*)&Qs[(sr + 32) * LSTR + sj] = *(const uint4*)&qhead[(size_t)(q0 + sr + 32) * HD + sj];
    __syncthreads();

    bf16x8 aq0 = *(const bf16x8*)&Qs[(16 * w + c) * LSTR + g * 8];
    bf16x8 aq1 = *(const bf16x8*)&Qs[(16 * w + c) * LSTR + 32 + g * 8];

    float m_i[4], l_i[4];
    floatx4 o[4];
#pragma unroll
    for (int i = 0; i < 4; ++i) { m_i[i] = -INFINITY; l_i[i] = 0.f; }
#pragma unroll
    for (int js = 0; js < 4; ++js) o[js] = (floatx4){0.f, 0.f, 0.f, 0.f};

    for (int k0 = 0; k0 < L; k0 += 64) {
        __syncthreads();
        *(uint4*)&Ks[sr * LSTR + sj]        = *(const uint4*)&khead[(size_t)(k0 + sr) * HD + sj];
        *(uint4*)&Ks[(sr + 32) * LSTR + sj] = *(const uint4*)&khead[(size_t)(k0 + sr + 32) * HD + sj];
        *(uint4*)&Vt[sr * LSTR + sj]        = *(const uint4*)&vhead[(size_t)sr * L + k0 + sj];
        *(uint4*)&Vt[(sr + 32) * LSTR + sj] = *(const uint4*)&vhead[(size_t)(sr + 32) * L + k0 + sj];
        __syncthreads();

        floatx4 s[4];
#pragma unroll
        for (int js = 0; js < 4; ++js) {
            floatx4 a2 = (floatx4){0.f, 0.f, 0.f, 0.f};
            a2 = __builtin_amdgcn_mfma_f32_16x16x32_bf16(aq0,
                    *(const bf16x8*)&Ks[(16 * js + c) * LSTR + g * 8], a2, 0, 0, 0);
            a2 = __builtin_amdgcn_mfma_f32_16x16x32_bf16(aq1,
                    *(const bf16x8*)&Ks[(16 * js + c) * LSTR + 32 + g * 8], a2, 0, 0, 0);
            s[js] = a2;
        }

        float alpha[4];
#pragma unroll
        for (int i = 0; i < 4; ++i) {
            float rm = fmaxf(fmaxf(s[0][i], s[1][i]), fmaxf(s[2][i], s[3][i]));
#pragma unroll
            for (int off = 1; off < 16; off <<= 1)
                rm = fmaxf(rm, __shfl_xor(rm, off, 16));
            float mn = fmaxf(m_i[i], rm);
            float al = __expf(m_i[i] - mn);
            float rs = 0.f;
#pragma unroll
            for (int js = 0; js < 4; ++js) {
                float pv = __expf(s[js][i] - mn);
                Ps[(16 * w + 4 * g + i) * LSTR + 16 * js + c] = f2bf(pv);
                rs += pv;
            }
#pragma unroll
            for (int off = 1; off < 16; off <<= 1)
                rs += __shfl_xor(rs, off, 16);
            l_i[i] = l_i[i] * al + rs;
            m_i[i] = mn;
            alpha[i] = al;
        }
#pragma unroll
        for (int js = 0; js < 4; ++js)
#pragma unroll
            for (int i = 0; i < 4; ++i)
                o[js][i] *= alpha[i];

        asm volatile("s_waitcnt lgkmcnt(0)" ::: "memory");  // wave-private P round-trip

        bf16x8 ap0 = *(const bf16x8*)&Ps[(16 * w + c) * LSTR + g * 8];
        bf16x8 ap1 = *(const bf16x8*)&Ps[(16 * w + c) * LSTR + 32 + g * 8];

#pragma unroll
        for (int js = 0; js < 4; ++js) {
            o[js] = __builtin_amdgcn_mfma_f32_16x16x32_bf16(ap0,
                      *(const bf16x8*)&Vt[(16 * js + c) * LSTR + g * 8], o[js], 0, 0, 0);
            o[js] = __builtin_amdgcn_mfma_f32_16x16x32_bf16(ap1,
                      *(const bf16x8*)&Vt[(16 * js + c) * LSTR + 32 + g * 8], o[js], 0, 0, 0);
        }
    }

    // ---- epilogue: normalize, split hi/lo, write [B,L,E] ----
#pragma unroll
    for (int i = 0; i < 4; ++i) {
        float inv = 1.f / l_i[i];
        int row = q0 + 16 * w + 4 * g + i;
        size_t base = ((size_t)(b * L + row)) * E + h * HD + c;
#pragma unroll
        for (int js = 0; js < 4; ++js) {
            float val = o[js][i] * inv;
            ushort hv = f2bf(val);
            attn_h[base + 16 * js] = hv;
            attn_l[base + 16 * js] = f2bf(val - bf2f(hv));
        }
    }
}

extern "C" void kernel_launch(void* const* d_in, const int* in_sizes, int n_in,
                              void* d_out, int out_size, void* d_ws, size_t ws_size,
                              hipStream_t stream) {
    const float* x    = (const float*)d_in[0];
    const float* cosT = (const float*)d_in[1];
    const float* sinT = (const float*)d_in[2];
    const float* Wqkv = (const float*)d_in[3];
    const float* bqkv = (const float*)d_in[4];
    const float* Wout = (const float*)d_in[5];
    const float* bout = (const float*)d_in[6];
    float* out = (float*)d_out;

    const size_t NX = (size_t)MROWS * E;     // 8388608 elements
    ushort* us  = (ushort*)d_ws;
    ushort* qh  = us;                        // [B,H,L,HD] roped+scaled q
    ushort* kh  = us + NX;                   // [B,H,L,HD] roped k
    ushort* vT  = us + 2 * NX;               // [B,H,HD,L] v transposed
    ushort* xh  = us + 3 * NX;               // x hi
    ushort* xl  = us + 4 * NX;               // x lo
    ushort* wqh = us + 5 * NX;               // Wqkv hi
    ushort* wql = wqh + (size_t)E3 * E;
    ushort* woh = wql + (size_t)E3 * E;      // Wout hi
    ushort* wol = woh + (size_t)E * E;
    ushort* ah  = xh;                        // attn hi/lo reuse x buffers
    ushort* al  = xl;                        //  (x consumed by gemm1 already)

    split_hl<<<(int)(NX / 4 / 256), 256, 0, stream>>>(x, xh, xl, (int)(NX / 4));
    split_hl<<<(int)((size_t)E3 * E / 4 / 256), 256, 0, stream>>>(Wqkv, wqh, wql, (int)((size_t)E3 * E / 4));
    split_hl<<<(int)((size_t)E * E / 4 / 256), 256, 0, stream>>>(Wout, woh, wol, (int)((size_t)E * E / 4));

    gemm_split<1><<<dim3(E3 / 128, MROWS / 128), 256, 0, stream>>>(
        xh, xl, wqh, wql, bqkv, nullptr, qh, kh, vT, cosT, sinT, E3, E);

    flash_mfma<<<dim3(B * H, L / 64), 256, 0, stream>>>(qh, kh, vT, ah, al);

    gemm_split<2><<<dim3(E / 128, MROWS / 128), 256, 0, stream>>>(
        ah, al, woh, wol, bout, out, nullptr, nullptr, nullptr, nullptr, nullptr, E, E);
}

// Round 4
// 472.418 us; speedup vs baseline: 5.5759x; 1.1828x over previous
//
#include <hip/hip_runtime.h>
#include <math.h>

#define B 4
#define L 2048
#define E 1024
#define H 16
#define HD 64
#define MROWS (B*L)      // 8192
#define E3 (3*E)         // 3072
#define LSTR 72

using bf16x8   = __attribute__((ext_vector_type(8))) short;
using floatx4  = __attribute__((ext_vector_type(4))) float;
using floatx16 = __attribute__((ext_vector_type(16))) float;

__device__ inline ushort f2bf(float x) {
    uint u = __float_as_uint(x);
    u += 0x7FFF + ((u >> 16) & 1);     // RNE
    return (ushort)(u >> 16);
}
__device__ inline float bf2f(ushort h) { return __uint_as_float(((uint)h) << 16); }

__device__ inline void async16(const void* g, void* l) {
    __builtin_amdgcn_global_load_lds(
        (const __attribute__((address_space(1))) uint*)g,
        (__attribute__((address_space(3))) uint*)l, 16, 0, 0);
}

// pack two fp32 -> {bf16(odd),bf16(even)} with RTZ in one v_perm
__device__ inline uint pack_rtz(float odd, float even) {
    return __builtin_amdgcn_perm(__float_as_uint(odd), __float_as_uint(even), 0x07060302u);
}

// ------------------------------------------------------------------
// fp32 -> bf16 hi/lo split
// ------------------------------------------------------------------
__global__ __launch_bounds__(256) void split_hl(const float* __restrict__ src,
        ushort* __restrict__ hi, ushort* __restrict__ lo, int n4)
{
    int i = blockIdx.x * 256 + threadIdx.x;
    if (i >= n4) return;
    float4 v = ((const float4*)src)[i];
    ushort4 hv, lv;
    hv.x = f2bf(v.x); lv.x = f2bf(v.x - bf2f(hv.x));
    hv.y = f2bf(v.y); lv.y = f2bf(v.y - bf2f(hv.y));
    hv.z = f2bf(v.z); lv.z = f2bf(v.z - bf2f(hv.z));
    hv.w = f2bf(v.w); lv.w = f2bf(v.w - bf2f(hv.w));
    ((ushort4*)hi)[i] = hv;
    ((ushort4*)lo)[i] = lv;
}

// ------------------------------------------------------------------
// Split-bf16 3-pass MFMA GEMM (unchanged from R3 — at structure plateau)
// ------------------------------------------------------------------
template<int MODE>
__global__ __launch_bounds__(256) void gemm_split(
        const ushort* __restrict__ Ah, const ushort* __restrict__ Al,
        const ushort* __restrict__ Bh, const ushort* __restrict__ Bl,
        const float* __restrict__ bias, float* __restrict__ Cf,
        ushort* __restrict__ qh, ushort* __restrict__ kh, ushort* __restrict__ vT,
        const float* __restrict__ cosT, const float* __restrict__ sinT,
        int Ndim, int Kdim)
{
    __shared__ ushort lds[16384];

    const int tid = threadIdx.x;
    const int w = tid >> 6, lane = tid & 63;
    const int g = lane >> 4, c = lane & 15;
    const int m0 = blockIdx.y * 128, n0 = blockIdx.x * 128;
    const int wm = w & 1, wn = w >> 1;

    const int rl0 = lane >> 2;
    const int jsw = (lane & 3) ^ ((lane >> 3) & 3);
    const ushort* gbase =
        (w == 0) ? Ah + (size_t)m0 * Kdim :
        (w == 1) ? Al + (size_t)m0 * Kdim :
        (w == 2) ? Bh + (size_t)n0 * Kdim :
                   Bl + (size_t)n0 * Kdim;
    const ushort* lanesrc = gbase + (size_t)rl0 * Kdim + jsw * 8;
    ushort* ldst = &lds[w * 4096];

    floatx4 acc[4][4];
#pragma unroll
    for (int a = 0; a < 4; ++a)
#pragma unroll
        for (int bq = 0; bq < 4; ++bq) acc[a][bq] = (floatx4){0.f, 0.f, 0.f, 0.f};

    const int swz  = (g ^ ((c >> 1) & 3)) * 8;
    const int arow = wm * 2048 + c * 32;
    const int brow = 8192 + wn * 2048 + c * 32;

    for (int k0 = 0; k0 < Kdim; k0 += 32) {
        __syncthreads();
#pragma unroll
        for (int p = 0; p < 8; ++p)
            async16(lanesrc + (size_t)p * 16 * Kdim + k0, ldst + p * 512);
        asm volatile("s_waitcnt vmcnt(0)" ::: "memory");
        __syncthreads();

        bf16x8 ah[4], alo[4], bh[4], blo[4];
#pragma unroll
        for (int t = 0; t < 4; ++t) {
            ah[t]  = *(const bf16x8*)&lds[arow + t * 512 + swz];
            alo[t] = *(const bf16x8*)&lds[4096 + arow + t * 512 + swz];
            bh[t]  = *(const bf16x8*)&lds[brow + t * 512 + swz];
            blo[t] = *(const bf16x8*)&lds[4096 + brow + t * 512 + swz];
        }
#pragma unroll
        for (int mt = 0; mt < 4; ++mt)
#pragma unroll
            for (int nt = 0; nt < 4; ++nt) {
                acc[mt][nt] = __builtin_amdgcn_mfma_f32_16x16x32_bf16(ah[mt],  bh[nt],  acc[mt][nt], 0, 0, 0);
                acc[mt][nt] = __builtin_amdgcn_mfma_f32_16x16x32_bf16(alo[mt], bh[nt],  acc[mt][nt], 0, 0, 0);
                acc[mt][nt] = __builtin_amdgcn_mfma_f32_16x16x32_bf16(ah[mt],  blo[nt], acc[mt][nt], 0, 0, 0);
            }
    }

    const int colbase = n0 + wn * 64;
#pragma unroll
    for (int mt = 0; mt < 4; ++mt) {
        const int rowb = m0 + wm * 64 + mt * 16 + g * 4;
        if constexpr (MODE == 2) {
#pragma unroll
            for (int i = 0; i < 4; ++i) {
                const int row = rowb + i;
#pragma unroll
                for (int nt = 0; nt < 4; ++nt) {
                    const int col = colbase + nt * 16 + c;
                    Cf[(size_t)row * Ndim + col] = acc[mt][nt][i] + bias[col];
                }
            }
        } else {
            const int sec = colbase >> 10;
            const int hg  = (colbase & 1023) >> 6;
#pragma unroll
            for (int i = 0; i < 4; ++i) {
                const int row = rowb + i;
                const int bb = row >> 11;
                const int l  = row & (L - 1);
                if (sec < 2) {
                    ushort* dst = (sec == 0 ? qh : kh) + ((size_t)(bb * H + hg) * L + l) * HD;
                    const float qs = (sec == 0) ? 0.125f : 1.0f;
#pragma unroll
                    for (int nt = 0; nt < 2; ++nt) {
                        const int d = nt * 16 + c;
                        float v1 = acc[mt][nt][i]     + bias[colbase + d];
                        float v2 = acc[mt][nt + 2][i] + bias[colbase + d + 32];
                        float cs = cosT[l * 32 + d], sn = sinT[l * 32 + d];
                        dst[d]      = f2bf((v1 * cs - v2 * sn) * qs);
                        dst[d + 32] = f2bf((v1 * sn + v2 * cs) * qs);
                    }
                } else {
#pragma unroll
                    for (int nt = 0; nt < 4; ++nt) {
                        const int d = nt * 16 + c;
                        float v = acc[mt][nt][i] + bias[colbase + d];
                        vT[((size_t)(bb * H + hg) * HD + d) * L + l] = f2bf(v);
                    }
                }
            }
        }
    }
}

// ------------------------------------------------------------------
// Flash attention v2: 32x32x16 MFMA, S^T/O^T orientation (q on lane dim
// throughout -> scalar stats, no P LDS round-trip), reg double-buffered
// K/V staging, 1 barrier per k-tile. Block = 256 thr, 128 q-rows.
// ------------------------------------------------------------------
__global__ __launch_bounds__(256, 3) void flash_mfma2(
        const ushort* __restrict__ qh, const ushort* __restrict__ kh,
        const ushort* __restrict__ vT,
        ushort* __restrict__ attn_h, ushort* __restrict__ attn_l)
{
    __shared__ ushort Ks[2][64 * LSTR];
    __shared__ ushort Vt[2][64 * LSTR];

    const int tid  = threadIdx.x;
    const int w    = tid >> 6;
    const int lane = tid & 63;
    const int h    = lane >> 5;        // half
    const int n    = lane & 31;
    const int b    = blockIdx.x >> 4;
    const int hd   = blockIdx.x & 15;
    const int q0   = blockIdx.y * 128;

    const ushort* khead = kh + (size_t)(b * H + hd) * L * HD;
    const ushort* vhead = vT + (size_t)(b * H + hd) * HD * L;

    // ---- Q A/B-frags straight from global (pre-roped, pre-scaled) ----
    const int q = q0 + 32 * w + n;
    const ushort* qptr = qh + ((size_t)(b * H + hd) * L + q) * HD + 8 * h;
    bf16x8 aq[4];
#pragma unroll
    for (int kd = 0; kd < 4; ++kd)
        aq[kd] = *(const bf16x8*)(qptr + 16 * kd);

    // ---- staging addresses ----
    const int sr = tid >> 3, sj8 = (tid & 7) * 8;
    const ushort* ks0 = khead + (size_t)sr * HD + sj8;          // + 64*t*HD
    const ushort* vs0 = vhead + (size_t)sr * L + sj8;           // + 64*t
    ushort* kw0 = &Ks[0][sr * LSTR + sj8];
    ushort* kw1 = &Ks[0][(sr + 32) * LSTR + sj8];
    ushort* vw0 = &Vt[0][sr * LSTR + sj8];
    ushort* vw1 = &Vt[0][(sr + 32) * LSTR + sj8];
    const int bufoff = 64 * LSTR;   // ushorts between buffer 0 and 1

    uint4 kr0, kr1, vr0, vr1;
    // prologue: tile 0 -> regs -> buf0 ; tile 1 -> regs
    kr0 = *(const uint4*)(ks0);
    kr1 = *(const uint4*)(ks0 + 32 * HD);
    vr0 = *(const uint4*)(vs0);
    vr1 = *(const uint4*)(vs0 + (size_t)32 * L);
    *(uint4*)kw0 = kr0; *(uint4*)kw1 = kr1;
    *(uint4*)vw0 = vr0; *(uint4*)vw1 = vr1;
    kr0 = *(const uint4*)(ks0 + (size_t)64 * HD);
    kr1 = *(const uint4*)(ks0 + (size_t)96 * HD);
    vr0 = *(const uint4*)(vs0 + 64);
    vr1 = *(const uint4*)(vs0 + (size_t)32 * L + 64);
    __syncthreads();

    float m_i = -INFINITY, l_i = 0.f;
    floatx16 o[2];
    o[0] = (floatx16)(0.f);
    o[1] = (floatx16)(0.f);

    const int NIT = L / 64;   // 32
    for (int it = 0; it < NIT; ++it) {
        const int p = it & 1;
        const ushort* KsC = &Ks[0][p * bufoff];
        const ushort* VtC = &Vt[0][p * bufoff];

        // write tile it+1 (held in regs) into the other buffer
        if (it + 1 < NIT) {
            const int po = (p ^ 1) * bufoff;
            *(uint4*)(kw0 + po) = kr0; *(uint4*)(kw1 + po) = kr1;
            *(uint4*)(vw0 + po) = vr0; *(uint4*)(vw1 + po) = vr1;
        }
        // issue loads for tile it+2
        if (it + 2 < NIT) {
            const size_t t = (size_t)(it + 2) * 64;
            kr0 = *(const uint4*)(ks0 + t * HD);
            kr1 = *(const uint4*)(ks0 + (t + 32) * HD);
            vr0 = *(const uint4*)(vs0 + t);
            vr1 = *(const uint4*)(vs0 + (size_t)32 * L + t);
        }

        // ---- two 32-kcol halves, each a full online-softmax update ----
#pragma unroll
        for (int js = 0; js < 2; ++js) {
            // S^T = K . Q^T  (A = K-frag, B = Q-frag)
            floatx16 s = (floatx16)(0.f);
#pragma unroll
            for (int kd = 0; kd < 4; ++kd) {
                bf16x8 kf = *(const bf16x8*)&KsC[(32 * js + n) * LSTR + 16 * kd + 8 * h];
                s = __builtin_amdgcn_mfma_f32_32x32x16_bf16(kf, aq[kd], s, 0, 0, 0);
            }

            // online softmax (per-lane scalar stats, q = lane&31)
            float rm = s[0];
#pragma unroll
            for (int r = 1; r < 16; ++r) rm = fmaxf(rm, s[r]);
            rm = fmaxf(rm, __shfl_xor(rm, 32, 64));
            float mn = fmaxf(m_i, rm);
            float al = __expf(m_i - mn);
            float pv[16]; float rs = 0.f;
#pragma unroll
            for (int r = 0; r < 16; ++r) { pv[r] = __expf(s[r] - mn); rs += pv[r]; }
            rs += __shfl_xor(rs, 32, 64);
            l_i = l_i * al + rs;
            m_i = mn;
            o[0] *= al; o[1] *= al;

            // pack P pairs: pku[rr][p2] = {bf(pv_odd),bf(pv_even)} (RTZ)
            uint pku[4][2];
#pragma unroll
            for (int rr = 0; rr < 4; ++rr) {
                pku[rr][0] = pack_rtz(pv[4 * rr + 1], pv[4 * rr + 0]);
                pku[rr][1] = pack_rtz(pv[4 * rr + 3], pv[4 * rr + 2]);
            }

            // C-layout -> B-frag exchange across lane^32
            uint bp_u[2][4];
#pragma unroll
            for (int f = 0; f < 2; ++f) {
                const int rA = 2 * f, rB = 2 * f + 1;
                uint mm0 = h ? pku[rB][0] : pku[rA][0];
                uint mm1 = h ? pku[rB][1] : pku[rA][1];
                uint mp0 = h ? pku[rA][0] : pku[rB][0];
                uint mp1 = h ? pku[rA][1] : pku[rB][1];
                uint g0 = (uint)__shfl_xor((int)mp0, 32, 64);
                uint g1 = (uint)__shfl_xor((int)mp1, 32, 64);
                bp_u[f][0] = h ? g0 : mm0;
                bp_u[f][1] = h ? g1 : mm1;
                bp_u[f][2] = h ? mm0 : g0;
                bp_u[f][3] = h ? mm1 : g1;
            }

            // O^T += V^T . P^T  (A = V-frag, B = P-frag)
#pragma unroll
            for (int f = 0; f < 2; ++f) {
                bf16x8 bp = *(const bf16x8*)&bp_u[f][0];
#pragma unroll
                for (int nt = 0; nt < 2; ++nt) {
                    bf16x8 vf = *(const bf16x8*)&VtC[(32 * nt + n) * LSTR + 32 * js + 16 * f + 8 * h];
                    o[nt] = __builtin_amdgcn_mfma_f32_32x32x16_bf16(vf, bp, o[nt], 0, 0, 0);
                }
            }
        }
        __syncthreads();
    }

    // ---- epilogue: normalize, split hi/lo, write attn [B,L,E] ----
    const float inv = 1.f / l_i;
    const size_t rowbase = ((size_t)(b * L + q)) * E + hd * HD;
#pragma unroll
    for (int nt = 0; nt < 2; ++nt)
#pragma unroll
        for (int rr = 0; rr < 4; ++rr) {
            const int d0 = 32 * nt + 8 * rr + 4 * h;
            float v0 = o[nt][4 * rr + 0] * inv;
            float v1 = o[nt][4 * rr + 1] * inv;
            float v2 = o[nt][4 * rr + 2] * inv;
            float v3 = o[nt][4 * rr + 3] * inv;
            ushort h0 = f2bf(v0), h1 = f2bf(v1), h2 = f2bf(v2), h3 = f2bf(v3);
            uint2 hw, lw;
            hw.x = (uint)h0 | ((uint)h1 << 16);
            hw.y = (uint)h2 | ((uint)h3 << 16);
            lw.x = (uint)f2bf(v0 - bf2f(h0)) | ((uint)f2bf(v1 - bf2f(h1)) << 16);
            lw.y = (uint)f2bf(v2 - bf2f(h2)) | ((uint)f2bf(v3 - bf2f(h3)) << 16);
            *(uint2*)&attn_h[rowbase + d0] = hw;
            *(uint2*)&attn_l[rowbase + d0] = lw;
        }
}

extern "C" void kernel_launch(void* const* d_in, const int* in_sizes, int n_in,
                              void* d_out, int out_size, void* d_ws, size_t ws_size,
                              hipStream_t stream) {
    const float* x    = (const float*)d_in[0];
    const float* cosT = (const float*)d_in[1];
    const float* sinT = (const float*)d_in[2];
    const float* Wqkv = (const float*)d_in[3];
    const float* bqkv = (const float*)d_in[4];
    const float* Wout = (const float*)d_in[5];
    const float* bout = (const float*)d_in[6];
    float* out = (float*)d_out;

    const size_t NX = (size_t)MROWS * E;
    ushort* us  = (ushort*)d_ws;
    ushort* qh  = us;                        // [B,H,L,HD] roped+scaled q
    ushort* kh  = us + NX;                   // [B,H,L,HD] roped k
    ushort* vTp = us + 2 * NX;               // [B,H,HD,L] v transposed
    ushort* xh  = us + 3 * NX;
    ushort* xl  = us + 4 * NX;
    ushort* wqh = us + 5 * NX;
    ushort* wql = wqh + (size_t)E3 * E;
    ushort* woh = wql + (size_t)E3 * E;
    ushort* wol = woh + (size_t)E * E;
    ushort* ah  = xh;                        // attn hi/lo reuse x buffers
    ushort* al  = xl;

    split_hl<<<(int)(NX / 4 / 256), 256, 0, stream>>>(x, xh, xl, (int)(NX / 4));
    split_hl<<<(int)((size_t)E3 * E / 4 / 256), 256, 0, stream>>>(Wqkv, wqh, wql, (int)((size_t)E3 * E / 4));
    split_hl<<<(int)((size_t)E * E / 4 / 256), 256, 0, stream>>>(Wout, woh, wol, (int)((size_t)E * E / 4));

    gemm_split<1><<<dim3(E3 / 128, MROWS / 128), 256, 0, stream>>>(
        xh, xl, wqh, wql, bqkv, nullptr, qh, kh, vTp, cosT, sinT, E3, E);

    flash_mfma2<<<dim3(B * H, L / 128), 256, 0, stream>>>(qh, kh, vTp, ah, al);

    gemm_split<2><<<dim3(E / 128, MROWS / 128), 256, 0, stream>>>(
        ah, al, woh, wol, bout, out, nullptr, nullptr, nullptr, nullptr, nullptr, E, E);
}

// Round 5
// 362.911 us; speedup vs baseline: 7.2584x; 1.3017x over previous
//
#include <hip/hip_runtime.h>
#include <math.h>

#define B 4
#define L 2048
#define E 1024
#define H 16
#define HD 64
#define MROWS (B*L)      // 8192
#define E3 (3*E)         // 3072
#define LSTR 72

using bf16x8   = __attribute__((ext_vector_type(8))) short;
using f16x8    = __attribute__((ext_vector_type(8))) _Float16;
using floatx4  = __attribute__((ext_vector_type(4))) float;
using floatx16 = __attribute__((ext_vector_type(16))) float;

__device__ inline ushort f2bf(float x) {
    uint u = __float_as_uint(x);
    u += 0x7FFF + ((u >> 16) & 1);     // RNE
    return (ushort)(u >> 16);
}
__device__ inline float bf2f(ushort h) { return __uint_as_float(((uint)h) << 16); }
__device__ inline ushort f2h(float x) { _Float16 h = (_Float16)x; return *(ushort*)&h; }

__device__ inline void async16(const void* g, void* l) {
    __builtin_amdgcn_global_load_lds(
        (const __attribute__((address_space(1))) uint*)g,
        (__attribute__((address_space(3))) uint*)l, 16, 0, 0);
}

// pack two fp32 -> {bf16(odd),bf16(even)} with RTZ in one v_perm
__device__ inline uint pack_rtz(float odd, float even) {
    return __builtin_amdgcn_perm(__float_as_uint(odd), __float_as_uint(even), 0x07060302u);
}

// ------------------------------------------------------------------
// fp32 -> fp16 convert (RNE)
// ------------------------------------------------------------------
__global__ __launch_bounds__(256) void cvt_h(const float* __restrict__ src,
        ushort* __restrict__ dst, int n4)
{
    int i = blockIdx.x * 256 + threadIdx.x;
    if (i >= n4) return;
    float4 v = ((const float4*)src)[i];
    ushort4 o;
    o.x = f2h(v.x); o.y = f2h(v.y); o.z = f2h(v.z); o.w = f2h(v.w);
    ((ushort4*)dst)[i] = o;
}

// ------------------------------------------------------------------
// Single-pass fp16 MFMA GEMM: C = A@Bw^T + bias. 128x128 tile, BK=32,
// 256 thr = 4 waves of 64x64. global_load_lds w=16, XOR-swizzled LDS.
// MODE 1: epilogue = bias + RoPE + scale, writes q,k [B,H,L,HD] bf16
//         and v transposed [B,H,HD,L] bf16.
// MODE 2: epilogue = bias, fp32 row-major out.
// ------------------------------------------------------------------
template<int MODE>
__global__ __launch_bounds__(256) void gemm_f16(
        const ushort* __restrict__ A16, const ushort* __restrict__ B16,
        const float* __restrict__ bias, float* __restrict__ Cf,
        ushort* __restrict__ qh, ushort* __restrict__ kh, ushort* __restrict__ vT,
        const float* __restrict__ cosT, const float* __restrict__ sinT,
        int Ndim, int Kdim)
{
    __shared__ ushort lds[8192];   // A tile | B tile (4096 ushorts each)

    const int tid = threadIdx.x;
    const int w = tid >> 6, lane = tid & 63;
    const int g = lane >> 4, c = lane & 15;
    const int m0 = blockIdx.y * 128, n0 = blockIdx.x * 128;
    const int wm = w & 1, wn = w >> 1;

    // wave w stages 64 rows: w0/w1 -> A halves, w2/w3 -> B halves
    const int rl0 = lane >> 2;
    const int jsw = (lane & 3) ^ ((lane >> 3) & 3);
    const ushort* gbase = (w < 2) ? A16 + (size_t)(m0 + 64 * (w & 1)) * Kdim
                                  : B16 + (size_t)(n0 + 64 * (w & 1)) * Kdim;
    const ushort* lanesrc = gbase + (size_t)rl0 * Kdim + jsw * 8;
    ushort* ldst = &lds[(w >> 1) * 4096 + (w & 1) * 2048];

    floatx4 acc[4][4];
#pragma unroll
    for (int a = 0; a < 4; ++a)
#pragma unroll
        for (int bq = 0; bq < 4; ++bq) acc[a][bq] = (floatx4){0.f, 0.f, 0.f, 0.f};

    const int swz  = (g ^ ((c >> 1) & 3)) * 8;
    const int arow = wm * 2048 + c * 32;
    const int brow = 4096 + wn * 2048 + c * 32;

    for (int k0 = 0; k0 < Kdim; k0 += 32) {
        __syncthreads();
#pragma unroll
        for (int p = 0; p < 4; ++p)
            async16(lanesrc + (size_t)p * 16 * Kdim + k0, ldst + p * 512);
        asm volatile("s_waitcnt vmcnt(0)" ::: "memory");
        __syncthreads();

        f16x8 af[4], bf[4];
#pragma unroll
        for (int t = 0; t < 4; ++t) {
            af[t] = *(const f16x8*)&lds[arow + t * 512 + swz];
            bf[t] = *(const f16x8*)&lds[brow + t * 512 + swz];
        }
#pragma unroll
        for (int mt = 0; mt < 4; ++mt)
#pragma unroll
            for (int nt = 0; nt < 4; ++nt)
                acc[mt][nt] = __builtin_amdgcn_mfma_f32_16x16x32_f16(af[mt], bf[nt], acc[mt][nt], 0, 0, 0);
    }

    // ---- epilogue; C/D: row = g*4+i, col = c (per 16x16 tile) ----
    const int colbase = n0 + wn * 64;
#pragma unroll
    for (int mt = 0; mt < 4; ++mt) {
        const int rowb = m0 + wm * 64 + mt * 16 + g * 4;
        if constexpr (MODE == 2) {
#pragma unroll
            for (int i = 0; i < 4; ++i) {
                const int row = rowb + i;
#pragma unroll
                for (int nt = 0; nt < 4; ++nt) {
                    const int col = colbase + nt * 16 + c;
                    Cf[(size_t)row * Ndim + col] = acc[mt][nt][i] + bias[col];
                }
            }
        } else {
            const int sec = colbase >> 10;             // 0=q 1=k 2=v
            const int hg  = (colbase & 1023) >> 6;
#pragma unroll
            for (int i = 0; i < 4; ++i) {
                const int row = rowb + i;
                const int bb = row >> 11;
                const int l  = row & (L - 1);
                if (sec < 2) {
                    ushort* dst = (sec == 0 ? qh : kh) + ((size_t)(bb * H + hg) * L + l) * HD;
                    const float qs = (sec == 0) ? 0.125f : 1.0f;
#pragma unroll
                    for (int nt = 0; nt < 2; ++nt) {
                        const int d = nt * 16 + c;
                        float v1 = acc[mt][nt][i]     + bias[colbase + d];
                        float v2 = acc[mt][nt + 2][i] + bias[colbase + d + 32];
                        float cs = cosT[l * 32 + d], sn = sinT[l * 32 + d];
                        dst[d]      = f2bf((v1 * cs - v2 * sn) * qs);
                        dst[d + 32] = f2bf((v1 * sn + v2 * cs) * qs);
                    }
                } else {
#pragma unroll
                    for (int nt = 0; nt < 4; ++nt) {
                        const int d = nt * 16 + c;
                        float v = acc[mt][nt][i] + bias[colbase + d];
                        vT[((size_t)(bb * H + hg) * HD + d) * L + l] = f2bf(v);
                    }
                }
            }
        }
    }
}

// ------------------------------------------------------------------
// Flash attention: 32x32x16 MFMA, S^T/O^T orientation, reg double-
// buffered K/V staging, 1 barrier per k-tile. Writes attn fp16 [B,L,E].
// ------------------------------------------------------------------
__global__ __launch_bounds__(256, 3) void flash_mfma2(
        const ushort* __restrict__ qh, const ushort* __restrict__ kh,
        const ushort* __restrict__ vT, ushort* __restrict__ attn16)
{
    __shared__ ushort Ks[2][64 * LSTR];
    __shared__ ushort Vt[2][64 * LSTR];

    const int tid  = threadIdx.x;
    const int w    = tid >> 6;
    const int lane = tid & 63;
    const int h    = lane >> 5;        // half
    const int n    = lane & 31;
    const int b    = blockIdx.x >> 4;
    const int hd   = blockIdx.x & 15;
    const int q0   = blockIdx.y * 128;

    const ushort* khead = kh + (size_t)(b * H + hd) * L * HD;
    const ushort* vhead = vT + (size_t)(b * H + hd) * HD * L;

    // ---- Q B-frags straight from global (pre-roped, pre-scaled) ----
    const int q = q0 + 32 * w + n;
    const ushort* qptr = qh + ((size_t)(b * H + hd) * L + q) * HD + 8 * h;
    bf16x8 aq[4];
#pragma unroll
    for (int kd = 0; kd < 4; ++kd)
        aq[kd] = *(const bf16x8*)(qptr + 16 * kd);

    // ---- staging addresses ----
    const int sr = tid >> 3, sj8 = (tid & 7) * 8;
    const ushort* ks0 = khead + (size_t)sr * HD + sj8;
    const ushort* vs0 = vhead + (size_t)sr * L + sj8;
    ushort* kw0 = &Ks[0][sr * LSTR + sj8];
    ushort* kw1 = &Ks[0][(sr + 32) * LSTR + sj8];
    ushort* vw0 = &Vt[0][sr * LSTR + sj8];
    ushort* vw1 = &Vt[0][(sr + 32) * LSTR + sj8];
    const int bufoff = 64 * LSTR;

    uint4 kr0, kr1, vr0, vr1;
    kr0 = *(const uint4*)(ks0);
    kr1 = *(const uint4*)(ks0 + 32 * HD);
    vr0 = *(const uint4*)(vs0);
    vr1 = *(const uint4*)(vs0 + (size_t)32 * L);
    *(uint4*)kw0 = kr0; *(uint4*)kw1 = kr1;
    *(uint4*)vw0 = vr0; *(uint4*)vw1 = vr1;
    kr0 = *(const uint4*)(ks0 + (size_t)64 * HD);
    kr1 = *(const uint4*)(ks0 + (size_t)96 * HD);
    vr0 = *(const uint4*)(vs0 + 64);
    vr1 = *(const uint4*)(vs0 + (size_t)32 * L + 64);
    __syncthreads();

    float m_i = -INFINITY, l_i = 0.f;
    floatx16 o[2];
    o[0] = (floatx16)(0.f);
    o[1] = (floatx16)(0.f);

    const int NIT = L / 64;   // 32
    for (int it = 0; it < NIT; ++it) {
        const int p = it & 1;
        const ushort* KsC = &Ks[0][p * bufoff];
        const ushort* VtC = &Vt[0][p * bufoff];

        if (it + 1 < NIT) {
            const int po = (p ^ 1) * bufoff;
            *(uint4*)(kw0 + po) = kr0; *(uint4*)(kw1 + po) = kr1;
            *(uint4*)(vw0 + po) = vr0; *(uint4*)(vw1 + po) = vr1;
        }
        if (it + 2 < NIT) {
            const size_t t = (size_t)(it + 2) * 64;
            kr0 = *(const uint4*)(ks0 + t * HD);
            kr1 = *(const uint4*)(ks0 + (t + 32) * HD);
            vr0 = *(const uint4*)(vs0 + t);
            vr1 = *(const uint4*)(vs0 + (size_t)32 * L + t);
        }

#pragma unroll
        for (int js = 0; js < 2; ++js) {
            // S^T = K . Q^T
            floatx16 s = (floatx16)(0.f);
#pragma unroll
            for (int kd = 0; kd < 4; ++kd) {
                bf16x8 kf = *(const bf16x8*)&KsC[(32 * js + n) * LSTR + 16 * kd + 8 * h];
                s = __builtin_amdgcn_mfma_f32_32x32x16_bf16(kf, aq[kd], s, 0, 0, 0);
            }

            float rm = s[0];
#pragma unroll
            for (int r = 1; r < 16; ++r) rm = fmaxf(rm, s[r]);
            rm = fmaxf(rm, __shfl_xor(rm, 32, 64));
            float mn = fmaxf(m_i, rm);
            float al = __expf(m_i - mn);
            float pv[16]; float rs = 0.f;
#pragma unroll
            for (int r = 0; r < 16; ++r) { pv[r] = __expf(s[r] - mn); rs += pv[r]; }
            rs += __shfl_xor(rs, 32, 64);
            l_i = l_i * al + rs;
            m_i = mn;
            o[0] *= al; o[1] *= al;

            uint pku[4][2];
#pragma unroll
            for (int rr = 0; rr < 4; ++rr) {
                pku[rr][0] = pack_rtz(pv[4 * rr + 1], pv[4 * rr + 0]);
                pku[rr][1] = pack_rtz(pv[4 * rr + 3], pv[4 * rr + 2]);
            }

            uint bp_u[2][4];
#pragma unroll
            for (int f = 0; f < 2; ++f) {
                const int rA = 2 * f, rB = 2 * f + 1;
                uint mm0 = h ? pku[rB][0] : pku[rA][0];
                uint mm1 = h ? pku[rB][1] : pku[rA][1];
                uint mp0 = h ? pku[rA][0] : pku[rB][0];
                uint mp1 = h ? pku[rA][1] : pku[rB][1];
                uint g0 = (uint)__shfl_xor((int)mp0, 32, 64);
                uint g1 = (uint)__shfl_xor((int)mp1, 32, 64);
                bp_u[f][0] = h ? g0 : mm0;
                bp_u[f][1] = h ? g1 : mm1;
                bp_u[f][2] = h ? mm0 : g0;
                bp_u[f][3] = h ? mm1 : g1;
            }

#pragma unroll
            for (int f = 0; f < 2; ++f) {
                bf16x8 bp = *(const bf16x8*)&bp_u[f][0];
#pragma unroll
                for (int nt = 0; nt < 2; ++nt) {
                    bf16x8 vf = *(const bf16x8*)&VtC[(32 * nt + n) * LSTR + 32 * js + 16 * f + 8 * h];
                    o[nt] = __builtin_amdgcn_mfma_f32_32x32x16_bf16(vf, bp, o[nt], 0, 0, 0);
                }
            }
        }
        __syncthreads();
    }

    // ---- epilogue: normalize, write attn fp16 [B,L,E] ----
    const float inv = 1.f / l_i;
    const size_t rowbase = ((size_t)(b * L + q)) * E + hd * HD;
#pragma unroll
    for (int nt = 0; nt < 2; ++nt)
#pragma unroll
        for (int rr = 0; rr < 4; ++rr) {
            const int d0 = 32 * nt + 8 * rr + 4 * h;
            ushort h0 = f2h(o[nt][4 * rr + 0] * inv);
            ushort h1 = f2h(o[nt][4 * rr + 1] * inv);
            ushort h2 = f2h(o[nt][4 * rr + 2] * inv);
            ushort h3 = f2h(o[nt][4 * rr + 3] * inv);
            uint2 hw;
            hw.x = (uint)h0 | ((uint)h1 << 16);
            hw.y = (uint)h2 | ((uint)h3 << 16);
            *(uint2*)&attn16[rowbase + d0] = hw;
        }
}

extern "C" void kernel_launch(void* const* d_in, const int* in_sizes, int n_in,
                              void* d_out, int out_size, void* d_ws, size_t ws_size,
                              hipStream_t stream) {
    const float* x    = (const float*)d_in[0];
    const float* cosT = (const float*)d_in[1];
    const float* sinT = (const float*)d_in[2];
    const float* Wqkv = (const float*)d_in[3];
    const float* bqkv = (const float*)d_in[4];
    const float* Wout = (const float*)d_in[5];
    const float* bout = (const float*)d_in[6];
    float* out = (float*)d_out;

    const size_t NX = (size_t)MROWS * E;
    ushort* us   = (ushort*)d_ws;
    ushort* qh   = us;                        // [B,H,L,HD] roped+scaled q (bf16)
    ushort* kh   = us + NX;                   // [B,H,L,HD] roped k (bf16)
    ushort* vTp  = us + 2 * NX;               // [B,H,HD,L] v transposed (bf16)
    ushort* x16  = us + 3 * NX;               // x fp16
    ushort* at16 = us + 4 * NX;               // attn fp16
    ushort* wq16 = us + 5 * NX;               // Wqkv fp16
    ushort* wo16 = wq16 + (size_t)E3 * E;     // Wout fp16

    cvt_h<<<(int)(NX / 4 / 256), 256, 0, stream>>>(x, x16, (int)(NX / 4));
    cvt_h<<<(int)((size_t)E3 * E / 4 / 256), 256, 0, stream>>>(Wqkv, wq16, (int)((size_t)E3 * E / 4));
    cvt_h<<<(int)((size_t)E * E / 4 / 256), 256, 0, stream>>>(Wout, wo16, (int)((size_t)E * E / 4));

    gemm_f16<1><<<dim3(E3 / 128, MROWS / 128), 256, 0, stream>>>(
        x16, wq16, bqkv, nullptr, qh, kh, vTp, cosT, sinT, E3, E);

    flash_mfma2<<<dim3(B * H, L / 128), 256, 0, stream>>>(qh, kh, vTp, at16);

    gemm_f16<2><<<dim3(E / 128, MROWS / 128), 256, 0, stream>>>(
        at16, wo16, bout, out, nullptr, nullptr, nullptr, nullptr, nullptr, E, E);
}

// Round 6
// 341.359 us; speedup vs baseline: 7.7167x; 1.0631x over previous
//
#include <hip/hip_runtime.h>
#include <math.h>

#define B 4
#define L 2048
#define E 1024
#define H 16
#define HD 64
#define MROWS (B*L)      // 8192
#define E3 (3*E)         // 3072
#define LSTR 72

using bf16x8   = __attribute__((ext_vector_type(8))) short;
using f16x8    = __attribute__((ext_vector_type(8))) _Float16;
using floatx4  = __attribute__((ext_vector_type(4))) float;
using floatx16 = __attribute__((ext_vector_type(16))) float;

__device__ inline ushort f2bf(float x) {
    uint u = __float_as_uint(x);
    u += 0x7FFF + ((u >> 16) & 1);     // RNE
    return (ushort)(u >> 16);
}
__device__ inline float bf2f(ushort h) { return __uint_as_float(((uint)h) << 16); }
__device__ inline ushort f2h(float x) { _Float16 h = (_Float16)x; return *(ushort*)&h; }

#if __has_builtin(__builtin_amdgcn_exp2f)
#define EXP2F(x) __builtin_amdgcn_exp2f(x)
#else
#define EXP2F(x) exp2f(x)
#endif

__device__ inline void async16(const void* g, void* l) {
    __builtin_amdgcn_global_load_lds(
        (const __attribute__((address_space(1))) uint*)g,
        (__attribute__((address_space(3))) uint*)l, 16, 0, 0);
}

// pack two fp32 -> {bf16(odd),bf16(even)} with RTZ in one v_perm
__device__ inline uint pack_rtz(float odd, float even) {
    return __builtin_amdgcn_perm(__float_as_uint(odd), __float_as_uint(even), 0x07060302u);
}

// ------------------------------------------------------------------
// fused fp32 -> fp16 convert of x | Wqkv | Wout (one launch)
// ------------------------------------------------------------------
#define N1Q ((size_t)MROWS * E / 4)        // x quads
#define N2Q ((size_t)E3 * E / 4)           // Wqkv quads
#define N3Q ((size_t)E * E / 4)            // Wout quads
__global__ __launch_bounds__(256) void cvt_all(
        const float* __restrict__ x, const float* __restrict__ wq,
        const float* __restrict__ wo, ushort* __restrict__ x16,
        ushort* __restrict__ wq16, ushort* __restrict__ wo16)
{
    size_t i = (size_t)blockIdx.x * 256 + threadIdx.x;
    const float* src; ushort* dst; size_t j;
    if (i < N1Q)                  { src = x;  dst = x16;  j = i; }
    else if (i < N1Q + N2Q)       { src = wq; dst = wq16; j = i - N1Q; }
    else                          { src = wo; dst = wo16; j = i - N1Q - N2Q; }
    float4 v = ((const float4*)src)[j];
    ushort4 o;
    o.x = f2h(v.x); o.y = f2h(v.y); o.z = f2h(v.z); o.w = f2h(v.w);
    ((ushort4*)dst)[j] = o;
}

// ------------------------------------------------------------------
// Single-pass fp16 MFMA GEMM: C = A@Bw^T + bias. 128x128 tile, BK=32,
// 256 thr = 4 waves of 64x64. global_load_lds w=16, XOR-swizzled LDS.
// MODE 1: epilogue = bias + RoPE, q scaled by 0.125*log2e, writes
//         q,k [B,H,L,HD] bf16 and v transposed [B,H,HD,L] bf16.
// MODE 2: epilogue = bias, fp32 row-major out.
// ------------------------------------------------------------------
template<int MODE>
__global__ __launch_bounds__(256) void gemm_f16(
        const ushort* __restrict__ A16, const ushort* __restrict__ B16,
        const float* __restrict__ bias, float* __restrict__ Cf,
        ushort* __restrict__ qh, ushort* __restrict__ kh, ushort* __restrict__ vT,
        const float* __restrict__ cosT, const float* __restrict__ sinT,
        int Ndim, int Kdim)
{
    __shared__ ushort lds[8192];   // A tile | B tile (4096 ushorts each)

    const int tid = threadIdx.x;
    const int w = tid >> 6, lane = tid & 63;
    const int g = lane >> 4, c = lane & 15;
    const int m0 = blockIdx.y * 128, n0 = blockIdx.x * 128;
    const int wm = w & 1, wn = w >> 1;

    const int rl0 = lane >> 2;
    const int jsw = (lane & 3) ^ ((lane >> 3) & 3);
    const ushort* gbase = (w < 2) ? A16 + (size_t)(m0 + 64 * (w & 1)) * Kdim
                                  : B16 + (size_t)(n0 + 64 * (w & 1)) * Kdim;
    const ushort* lanesrc = gbase + (size_t)rl0 * Kdim + jsw * 8;
    ushort* ldst = &lds[(w >> 1) * 4096 + (w & 1) * 2048];

    floatx4 acc[4][4];
#pragma unroll
    for (int a = 0; a < 4; ++a)
#pragma unroll
        for (int bq = 0; bq < 4; ++bq) acc[a][bq] = (floatx4){0.f, 0.f, 0.f, 0.f};

    const int swz  = (g ^ ((c >> 1) & 3)) * 8;
    const int arow = wm * 2048 + c * 32;
    const int brow = 4096 + wn * 2048 + c * 32;

    for (int k0 = 0; k0 < Kdim; k0 += 32) {
        __syncthreads();
#pragma unroll
        for (int p = 0; p < 4; ++p)
            async16(lanesrc + (size_t)p * 16 * Kdim + k0, ldst + p * 512);
        asm volatile("s_waitcnt vmcnt(0)" ::: "memory");
        __syncthreads();

        f16x8 af[4], bf[4];
#pragma unroll
        for (int t = 0; t < 4; ++t) {
            af[t] = *(const f16x8*)&lds[arow + t * 512 + swz];
            bf[t] = *(const f16x8*)&lds[brow + t * 512 + swz];
        }
#pragma unroll
        for (int mt = 0; mt < 4; ++mt)
#pragma unroll
            for (int nt = 0; nt < 4; ++nt)
                acc[mt][nt] = __builtin_amdgcn_mfma_f32_16x16x32_f16(af[mt], bf[nt], acc[mt][nt], 0, 0, 0);
    }

    // ---- epilogue; C/D: row = g*4+i, col = c (per 16x16 tile) ----
    const int colbase = n0 + wn * 64;
#pragma unroll
    for (int mt = 0; mt < 4; ++mt) {
        const int rowb = m0 + wm * 64 + mt * 16 + g * 4;
        if constexpr (MODE == 2) {
#pragma unroll
            for (int i = 0; i < 4; ++i) {
                const int row = rowb + i;
#pragma unroll
                for (int nt = 0; nt < 4; ++nt) {
                    const int col = colbase + nt * 16 + c;
                    Cf[(size_t)row * Ndim + col] = acc[mt][nt][i] + bias[col];
                }
            }
        } else {
            const int sec = colbase >> 10;             // 0=q 1=k 2=v
            const int hg  = (colbase & 1023) >> 6;
#pragma unroll
            for (int i = 0; i < 4; ++i) {
                const int row = rowb + i;
                const int bb = row >> 11;
                const int l  = row & (L - 1);
                if (sec < 2) {
                    ushort* dst = (sec == 0 ? qh : kh) + ((size_t)(bb * H + hg) * L + l) * HD;
                    // q carries softmax scale AND log2e for the exp2 softmax
                    const float qs = (sec == 0) ? 0.18033688f : 1.0f;
#pragma unroll
                    for (int nt = 0; nt < 2; ++nt) {
                        const int d = nt * 16 + c;
                        float v1 = acc[mt][nt][i]     + bias[colbase + d];
                        float v2 = acc[mt][nt + 2][i] + bias[colbase + d + 32];
                        float cs = cosT[l * 32 + d], sn = sinT[l * 32 + d];
                        dst[d]      = f2bf((v1 * cs - v2 * sn) * qs);
                        dst[d + 32] = f2bf((v1 * sn + v2 * cs) * qs);
                    }
                } else {
#pragma unroll
                    for (int nt = 0; nt < 4; ++nt) {
                        const int d = nt * 16 + c;
                        float v = acc[mt][nt][i] + bias[colbase + d];
                        vT[((size_t)(bb * H + hg) * HD + d) * L + l] = f2bf(v);
                    }
                }
            }
        }
    }
}

// ------------------------------------------------------------------
// Flash attention v3: fixed-shift streaming softmax (no online max).
// Scores arrive in log2 units (q pre-scaled by 0.125*log2e); the -16
// shift is folded into the MFMA C initializer; pv = v_exp_f32(s).
// 32x32x16 MFMA, S^T/O^T orientation, reg double-buffered staging.
// ------------------------------------------------------------------
__global__ __launch_bounds__(256, 3) void flash_mfma3(
        const ushort* __restrict__ qh, const ushort* __restrict__ kh,
        const ushort* __restrict__ vT, ushort* __restrict__ attn16)
{
    __shared__ ushort Ks[2][64 * LSTR];
    __shared__ ushort Vt[2][64 * LSTR];

    const int tid  = threadIdx.x;
    const int w    = tid >> 6;
    const int lane = tid & 63;
    const int h    = lane >> 5;        // half
    const int n    = lane & 31;
    const int b    = blockIdx.x >> 4;
    const int hd   = blockIdx.x & 15;
    const int q0   = blockIdx.y * 128;

    const ushort* khead = kh + (size_t)(b * H + hd) * L * HD;
    const ushort* vhead = vT + (size_t)(b * H + hd) * HD * L;

    const int q = q0 + 32 * w + n;
    const ushort* qptr = qh + ((size_t)(b * H + hd) * L + q) * HD + 8 * h;
    bf16x8 aq[4];
#pragma unroll
    for (int kd = 0; kd < 4; ++kd)
        aq[kd] = *(const bf16x8*)(qptr + 16 * kd);

    const int sr = tid >> 3, sj8 = (tid & 7) * 8;
    const ushort* ks0 = khead + (size_t)sr * HD + sj8;
    const ushort* vs0 = vhead + (size_t)sr * L + sj8;
    ushort* kw0 = &Ks[0][sr * LSTR + sj8];
    ushort* kw1 = &Ks[0][(sr + 32) * LSTR + sj8];
    ushort* vw0 = &Vt[0][sr * LSTR + sj8];
    ushort* vw1 = &Vt[0][(sr + 32) * LSTR + sj8];
    const int bufoff = 64 * LSTR;

    uint4 kr0, kr1, vr0, vr1;
    kr0 = *(const uint4*)(ks0);
    kr1 = *(const uint4*)(ks0 + 32 * HD);
    vr0 = *(const uint4*)(vs0);
    vr1 = *(const uint4*)(vs0 + (size_t)32 * L);
    *(uint4*)kw0 = kr0; *(uint4*)kw1 = kr1;
    *(uint4*)vw0 = vr0; *(uint4*)vw1 = vr1;
    kr0 = *(const uint4*)(ks0 + (size_t)64 * HD);
    kr1 = *(const uint4*)(ks0 + (size_t)96 * HD);
    vr0 = *(const uint4*)(vs0 + 64);
    vr1 = *(const uint4*)(vs0 + (size_t)32 * L + 64);
    __syncthreads();

    float l_i = 0.f;                  // per-lane partial (16 of 32 kpos/half)
    floatx16 o[2];
    o[0] = (floatx16)(0.f);
    o[1] = (floatx16)(0.f);

    const int NIT = L / 64;   // 32
    for (int it = 0; it < NIT; ++it) {
        const int p = it & 1;
        const ushort* KsC = &Ks[0][p * bufoff];
        const ushort* VtC = &Vt[0][p * bufoff];

        if (it + 1 < NIT) {
            const int po = (p ^ 1) * bufoff;
            *(uint4*)(kw0 + po) = kr0; *(uint4*)(kw1 + po) = kr1;
            *(uint4*)(vw0 + po) = vr0; *(uint4*)(vw1 + po) = vr1;
        }
        if (it + 2 < NIT) {
            const size_t t = (size_t)(it + 2) * 64;
            kr0 = *(const uint4*)(ks0 + t * HD);
            kr1 = *(const uint4*)(ks0 + (t + 32) * HD);
            vr0 = *(const uint4*)(vs0 + t);
            vr1 = *(const uint4*)(vs0 + (size_t)32 * L + t);
        }

#pragma unroll
        for (int js = 0; js < 2; ++js) {
            // S^T = K . Q^T - 16  (shift in C init)
            floatx16 s = (floatx16)(-16.0f);
#pragma unroll
            for (int kd = 0; kd < 4; ++kd) {
                bf16x8 kf = *(const bf16x8*)&KsC[(32 * js + n) * LSTR + 16 * kd + 8 * h];
                s = __builtin_amdgcn_mfma_f32_32x32x16_bf16(kf, aq[kd], s, 0, 0, 0);
            }

            // streaming softmax: pv = 2^s, no max, no rescale
            float pv[16]; float rs = 0.f;
#pragma unroll
            for (int r = 0; r < 16; ++r) { pv[r] = EXP2F(s[r]); rs += pv[r]; }
            l_i += rs;

            uint pku[4][2];
#pragma unroll
            for (int rr = 0; rr < 4; ++rr) {
                pku[rr][0] = pack_rtz(pv[4 * rr + 1], pv[4 * rr + 0]);
                pku[rr][1] = pack_rtz(pv[4 * rr + 3], pv[4 * rr + 2]);
            }

            // C-layout -> B-frag exchange across lane^32
            uint bp_u[2][4];
#pragma unroll
            for (int f = 0; f < 2; ++f) {
                const int rA = 2 * f, rB = 2 * f + 1;
                uint mm0 = h ? pku[rB][0] : pku[rA][0];
                uint mm1 = h ? pku[rB][1] : pku[rA][1];
                uint mp0 = h ? pku[rA][0] : pku[rB][0];
                uint mp1 = h ? pku[rA][1] : pku[rB][1];
                uint g0 = (uint)__shfl_xor((int)mp0, 32, 64);
                uint g1 = (uint)__shfl_xor((int)mp1, 32, 64);
                bp_u[f][0] = h ? g0 : mm0;
                bp_u[f][1] = h ? g1 : mm1;
                bp_u[f][2] = h ? mm0 : g0;
                bp_u[f][3] = h ? mm1 : g1;
            }

            // O^T += V^T . P^T
#pragma unroll
            for (int f = 0; f < 2; ++f) {
                bf16x8 bp = *(const bf16x8*)&bp_u[f][0];
#pragma unroll
                for (int nt = 0; nt < 2; ++nt) {
                    bf16x8 vf = *(const bf16x8*)&VtC[(32 * nt + n) * LSTR + 32 * js + 16 * f + 8 * h];
                    o[nt] = __builtin_amdgcn_mfma_f32_32x32x16_bf16(vf, bp, o[nt], 0, 0, 0);
                }
            }
        }
        __syncthreads();
    }

    // ---- epilogue: combine partner l, normalize, write fp16 [B,L,E] ----
    const float l_tot = l_i + __shfl_xor(l_i, 32, 64);
    const float inv = 1.f / l_tot;
    const size_t rowbase = ((size_t)(b * L + q)) * E + hd * HD;
#pragma unroll
    for (int nt = 0; nt < 2; ++nt)
#pragma unroll
        for (int rr = 0; rr < 4; ++rr) {
            const int d0 = 32 * nt + 8 * rr + 4 * h;
            ushort h0 = f2h(o[nt][4 * rr + 0] * inv);
            ushort h1 = f2h(o[nt][4 * rr + 1] * inv);
            ushort h2 = f2h(o[nt][4 * rr + 2] * inv);
            ushort h3 = f2h(o[nt][4 * rr + 3] * inv);
            uint2 hw;
            hw.x = (uint)h0 | ((uint)h1 << 16);
            hw.y = (uint)h2 | ((uint)h3 << 16);
            *(uint2*)&attn16[rowbase + d0] = hw;
        }
}

extern "C" void kernel_launch(void* const* d_in, const int* in_sizes, int n_in,
                              void* d_out, int out_size, void* d_ws, size_t ws_size,
                              hipStream_t stream) {
    const float* x    = (const float*)d_in[0];
    const float* cosT = (const float*)d_in[1];
    const float* sinT = (const float*)d_in[2];
    const float* Wqkv = (const float*)d_in[3];
    const float* bqkv = (const float*)d_in[4];
    const float* Wout = (const float*)d_in[5];
    const float* bout = (const float*)d_in[6];
    float* out = (float*)d_out;

    const size_t NX = (size_t)MROWS * E;
    ushort* us   = (ushort*)d_ws;
    ushort* qh   = us;                        // [B,H,L,HD] roped+scaled q (bf16)
    ushort* kh   = us + NX;                   // [B,H,L,HD] roped k (bf16)
    ushort* vTp  = us + 2 * NX;               // [B,H,HD,L] v transposed (bf16)
    ushort* x16  = us + 3 * NX;               // x fp16
    ushort* at16 = us + 4 * NX;               // attn fp16
    ushort* wq16 = us + 5 * NX;               // Wqkv fp16
    ushort* wo16 = wq16 + (size_t)E3 * E;     // Wout fp16

    const int cvt_blocks = (int)((N1Q + N2Q + N3Q + 255) / 256);
    cvt_all<<<cvt_blocks, 256, 0, stream>>>(x, Wqkv, Wout, x16, wq16, wo16);

    gemm_f16<1><<<dim3(E3 / 128, MROWS / 128), 256, 0, stream>>>(
        x16, wq16, bqkv, nullptr, qh, kh, vTp, cosT, sinT, E3, E);

    flash_mfma3<<<dim3(B * H, L / 128), 256, 0, stream>>>(qh, kh, vTp, at16);

    gemm_f16<2><<<dim3(E / 128, MROWS / 128), 256, 0, stream>>>(
        at16, wo16, bout, out, nullptr, nullptr, nullptr, nullptr, nullptr, E, E);
}

// Round 7
// 287.942 us; speedup vs baseline: 9.1482x; 1.1855x over previous
//
#include <hip/hip_runtime.h>
#include <math.h>

#define B 4
#define L 2048
#define E 1024
#define H 16
#define HD 64
#define MROWS (B*L)      // 8192
#define E3 (3*E)         // 3072

using bf16x8   = __attribute__((ext_vector_type(8))) short;
using f16x8    = __attribute__((ext_vector_type(8))) _Float16;
using floatx4  = __attribute__((ext_vector_type(4))) float;
using floatx16 = __attribute__((ext_vector_type(16))) float;

__device__ inline ushort f2bf(float x) {
    uint u = __float_as_uint(x);
    u += 0x7FFF + ((u >> 16) & 1);     // RNE
    return (ushort)(u >> 16);
}
__device__ inline float bf2f(ushort h) { return __uint_as_float(((uint)h) << 16); }
__device__ inline ushort f2h(float x) { _Float16 h = (_Float16)x; return *(ushort*)&h; }

#if __has_builtin(__builtin_amdgcn_exp2f)
#define EXP2F(x) __builtin_amdgcn_exp2f(x)
#else
#define EXP2F(x) exp2f(x)
#endif

__device__ inline void async16(const void* g, void* l) {
    __builtin_amdgcn_global_load_lds(
        (const __attribute__((address_space(1))) uint*)g,
        (__attribute__((address_space(3))) uint*)l, 16, 0, 0);
}

// pack two fp32 -> {bf16(odd),bf16(even)} with RTZ in one v_perm
__device__ inline uint pack_rtz(float odd, float even) {
    return __builtin_amdgcn_perm(__float_as_uint(odd), __float_as_uint(even), 0x07060302u);
}

// ------------------------------------------------------------------
// fused fp32 -> fp16 convert of x | Wqkv | Wout (one launch)
// ------------------------------------------------------------------
#define N1Q ((size_t)MROWS * E / 4)        // x quads
#define N2Q ((size_t)E3 * E / 4)           // Wqkv quads
#define N3Q ((size_t)E * E / 4)            // Wout quads
__global__ __launch_bounds__(256) void cvt_all(
        const float* __restrict__ x, const float* __restrict__ wq,
        const float* __restrict__ wo, ushort* __restrict__ x16,
        ushort* __restrict__ wq16, ushort* __restrict__ wo16)
{
    size_t i = (size_t)blockIdx.x * 256 + threadIdx.x;
    const float* src; ushort* dst; size_t j;
    if (i < N1Q)                  { src = x;  dst = x16;  j = i; }
    else if (i < N1Q + N2Q)       { src = wq; dst = wq16; j = i - N1Q; }
    else                          { src = wo; dst = wo16; j = i - N1Q - N2Q; }
    float4 v = ((const float4*)src)[j];
    ushort4 o;
    o.x = f2h(v.x); o.y = f2h(v.y); o.z = f2h(v.z); o.w = f2h(v.w);
    ((ushort4*)dst)[j] = o;
}

// ------------------------------------------------------------------
// Single-pass fp16 MFMA GEMM: C = A@Bw^T + bias. 128x128 tile, BK=32.
// MODE 1 epilogue: bias + RoPE (q also * 0.125*log2e); writes
//   q,k [B,H,L,HD] bf16 with 8-elem d-groups XOR-swizzled by (l&7),
//   v [B,H,HD,L] bf16 with kpos bit2<->bit3 swapped (PV frag order)
//   and kpos-groups XOR-swizzled by (d&7). These layouts make flash's
//   async-LDS staging linear AND its b128 frag reads bank-balanced.
// MODE 2 epilogue: bias, fp32 row-major out.
// ------------------------------------------------------------------
template<int MODE>
__global__ __launch_bounds__(256) void gemm_f16(
        const ushort* __restrict__ A16, const ushort* __restrict__ B16,
        const float* __restrict__ bias, float* __restrict__ Cf,
        ushort* __restrict__ qh, ushort* __restrict__ kh, ushort* __restrict__ vT,
        const float* __restrict__ cosT, const float* __restrict__ sinT,
        int Ndim, int Kdim)
{
    __shared__ ushort lds[8192];   // A tile | B tile (4096 ushorts each)

    const int tid = threadIdx.x;
    const int w = tid >> 6, lane = tid & 63;
    const int g = lane >> 4, c = lane & 15;
    const int m0 = blockIdx.y * 128, n0 = blockIdx.x * 128;
    const int wm = w & 1, wn = w >> 1;

    const int rl0 = lane >> 2;
    const int jsw = (lane & 3) ^ ((lane >> 3) & 3);
    const ushort* gbase = (w < 2) ? A16 + (size_t)(m0 + 64 * (w & 1)) * Kdim
                                  : B16 + (size_t)(n0 + 64 * (w & 1)) * Kdim;
    const ushort* lanesrc = gbase + (size_t)rl0 * Kdim + jsw * 8;
    ushort* ldst = &lds[(w >> 1) * 4096 + (w & 1) * 2048];

    floatx4 acc[4][4];
#pragma unroll
    for (int a = 0; a < 4; ++a)
#pragma unroll
        for (int bq = 0; bq < 4; ++bq) acc[a][bq] = (floatx4){0.f, 0.f, 0.f, 0.f};

    const int swz  = (g ^ ((c >> 1) & 3)) * 8;
    const int arow = wm * 2048 + c * 32;
    const int brow = 4096 + wn * 2048 + c * 32;

    for (int k0 = 0; k0 < Kdim; k0 += 32) {
        __syncthreads();
#pragma unroll
        for (int p = 0; p < 4; ++p)
            async16(lanesrc + (size_t)p * 16 * Kdim + k0, ldst + p * 512);
        asm volatile("s_waitcnt vmcnt(0)" ::: "memory");
        __syncthreads();

        f16x8 af[4], bf[4];
#pragma unroll
        for (int t = 0; t < 4; ++t) {
            af[t] = *(const f16x8*)&lds[arow + t * 512 + swz];
            bf[t] = *(const f16x8*)&lds[brow + t * 512 + swz];
        }
#pragma unroll
        for (int mt = 0; mt < 4; ++mt)
#pragma unroll
            for (int nt = 0; nt < 4; ++nt)
                acc[mt][nt] = __builtin_amdgcn_mfma_f32_16x16x32_f16(af[mt], bf[nt], acc[mt][nt], 0, 0, 0);
    }

    // ---- epilogue; C/D: row = g*4+i, col = c (per 16x16 tile) ----
    const int colbase = n0 + wn * 64;
#pragma unroll
    for (int mt = 0; mt < 4; ++mt) {
        const int rowb = m0 + wm * 64 + mt * 16 + g * 4;
        if constexpr (MODE == 2) {
#pragma unroll
            for (int i = 0; i < 4; ++i) {
                const int row = rowb + i;
#pragma unroll
                for (int nt = 0; nt < 4; ++nt) {
                    const int col = colbase + nt * 16 + c;
                    Cf[(size_t)row * Ndim + col] = acc[mt][nt][i] + bias[col];
                }
            }
        } else {
            const int sec = colbase >> 10;             // 0=q 1=k 2=v
            const int hg  = (colbase & 1023) >> 6;
#pragma unroll
            for (int i = 0; i < 4; ++i) {
                const int row = rowb + i;
                const int bb = row >> 11;
                const int l  = row & (L - 1);
                if (sec < 2) {
                    ushort* dst = (sec == 0 ? qh : kh) + ((size_t)(bb * H + hg) * L + l) * HD;
                    const int sw = l & 7;
                    // q carries softmax scale AND log2e for the exp2 softmax
                    const float qs = (sec == 0) ? 0.18033688f : 1.0f;
#pragma unroll
                    for (int nt = 0; nt < 2; ++nt) {
                        const int d  = nt * 16 + c;
                        const int d2 = d + 32;
                        float v1 = acc[mt][nt][i]     + bias[colbase + d];
                        float v2 = acc[mt][nt + 2][i] + bias[colbase + d2];
                        float cs = cosT[l * 32 + d], sn = sinT[l * 32 + d];
                        dst[(((d  >> 3) ^ sw) << 3) | (d  & 7)] = f2bf((v1 * cs - v2 * sn) * qs);
                        dst[(((d2 >> 3) ^ sw) << 3) | (d2 & 7)] = f2bf((v1 * sn + v2 * cs) * qs);
                    }
                } else {
                    // sigma: swap bits 2,3 of kpos; then group-swizzle by d&7
                    const int lp = (l & ~12) | ((l & 4) << 1) | ((l & 8) >> 1);
                    const int intile = ((((lp >> 3) & 7)) << 3);
#pragma unroll
                    for (int nt = 0; nt < 4; ++nt) {
                        const int d = nt * 16 + c;
                        float v = acc[mt][nt][i] + bias[colbase + d];
                        size_t idx = ((size_t)(bb * H + hg) * HD + d) * L
                                   + (l & ~63) + (intile ^ ((d & 7) << 3)) + (lp & 7);
                        vT[idx] = f2bf(v);
                    }
                }
            }
        }
    }
}

// ------------------------------------------------------------------
// Flash attention v4: fixed-shift streaming softmax; sigma-ordered V so
// P packs straight from MFMA regs (no cross-lane exchange); async
// global_load_lds double-buffered staging (prefetch issued after the
// barrier -> barrier never stalls on in-flight loads); swizzled global
// layouts give bank-balanced b128 LDS reads with linear staging.
// ------------------------------------------------------------------
__global__ __launch_bounds__(256, 4) void flash_mfma4(
        const ushort* __restrict__ qh, const ushort* __restrict__ kh,
        const ushort* __restrict__ vT, ushort* __restrict__ attn16)
{
    __shared__ ushort Ks[2][4096];   // [kpos 0..63][d-group swz] 8KB/buf
    __shared__ ushort Vt[2][4096];   // [d 0..63][kpos sigma+swz] 8KB/buf

    const int tid  = threadIdx.x;
    const int w    = tid >> 6;
    const int lane = tid & 63;
    const int h    = lane >> 5;
    const int n    = lane & 31;
    const int b    = blockIdx.x >> 4;
    const int hd   = blockIdx.x & 15;
    const int q0   = blockIdx.y * 128;

    const ushort* khead = kh + (size_t)(b * H + hd) * L * HD;
    const ushort* vhead = vT + (size_t)(b * H + hd) * HD * L;

    // ---- Q B-frags from global (swizzled groups) ----
    const int q = q0 + 32 * w + n;
    const ushort* qrow = qh + ((size_t)(b * H + hd) * L + q) * HD;
    bf16x8 aq[4];
#pragma unroll
    for (int kd = 0; kd < 4; ++kd)
        aq[kd] = *(const bf16x8*)&qrow[((2 * kd + h) ^ (q & 7)) << 3];

    // ---- staging sources: waves 0,1 -> K halves; waves 2,3 -> V halves
    const int wk = w & 1;
    const ushort* ksrc = khead + (size_t)(32 * wk) * 64 + lane * 8;              // +it*4096 +p*512
    const ushort* vsrc = vhead + (size_t)(32 * wk + (lane >> 3)) * L + (lane & 7) * 8;  // +it*64 +p*8*L

    const int NIT = L / 64;   // 32
    // prologue: stage tile 0 into buf 0
    if (w < 2) {
#pragma unroll
        for (int p = 0; p < 4; ++p)
            async16(ksrc + p * 512, &Ks[0][32 * wk * 64 + p * 512]);
    } else {
#pragma unroll
        for (int p = 0; p < 4; ++p)
            async16(vsrc + (size_t)p * 8 * L, &Vt[0][32 * wk * 64 + p * 512]);
    }

    float l_i = 0.f;
    floatx16 o[2];
    o[0] = (floatx16)(0.f);
    o[1] = (floatx16)(0.f);

    for (int it = 0; it < NIT; ++it) {
        const int p = it & 1;
        __syncthreads();   // drains this iter's (old) loads, syncs all waves

        // prefetch tile it+1 into the other buffer; flies during compute
        if (it + 1 < NIT) {
            if (w < 2) {
                const ushort* s = ksrc + (size_t)(it + 1) * 4096;
#pragma unroll
                for (int pp = 0; pp < 4; ++pp)
                    async16(s + pp * 512, &Ks[p ^ 1][32 * wk * 64 + pp * 512]);
            } else {
                const ushort* s = vsrc + (size_t)(it + 1) * 64;
#pragma unroll
                for (int pp = 0; pp < 4; ++pp)
                    async16(s + (size_t)pp * 8 * L, &Vt[p ^ 1][32 * wk * 64 + pp * 512]);
            }
        }

        const ushort* KsC = Ks[p];
        const ushort* VtC = Vt[p];

#pragma unroll
        for (int js = 0; js < 2; ++js) {
            // S^T = K . Q^T - 16  (shift folded into C init)
            floatx16 s = (floatx16)(-16.0f);
#pragma unroll
            for (int kd = 0; kd < 4; ++kd) {
                bf16x8 kf = *(const bf16x8*)&KsC[(32 * js + n) * 64 + (((2 * kd + h) ^ (n & 7)) << 3)];
                s = __builtin_amdgcn_mfma_f32_32x32x16_bf16(kf, aq[kd], s, 0, 0, 0);
            }

            // streaming softmax + direct-pack P (sigma order matches regs)
            float pv[16];
            float rs = 0.f;
#pragma unroll
            for (int rr = 0; rr < 4; ++rr) {
                float p0 = EXP2F(s[4 * rr + 0]);
                float p1 = EXP2F(s[4 * rr + 1]);
                float p2 = EXP2F(s[4 * rr + 2]);
                float p3 = EXP2F(s[4 * rr + 3]);
                pv[4 * rr + 0] = p0; pv[4 * rr + 1] = p1;
                pv[4 * rr + 2] = p2; pv[4 * rr + 3] = p3;
                rs += (p0 + p1) + (p2 + p3);
            }
            l_i += rs;

#pragma unroll
            for (int f = 0; f < 2; ++f) {
                uint bu[4];
                bu[0] = pack_rtz(pv[8 * f + 1], pv[8 * f + 0]);
                bu[1] = pack_rtz(pv[8 * f + 3], pv[8 * f + 2]);
                bu[2] = pack_rtz(pv[8 * f + 5], pv[8 * f + 4]);
                bu[3] = pack_rtz(pv[8 * f + 7], pv[8 * f + 6]);
                bf16x8 bp = *(const bf16x8*)&bu[0];
#pragma unroll
                for (int nt = 0; nt < 2; ++nt) {
                    bf16x8 vf = *(const bf16x8*)&VtC[(32 * nt + n) * 64 + (((4 * js + 2 * f + h) ^ (n & 7)) << 3)];
                    o[nt] = __builtin_amdgcn_mfma_f32_32x32x16_bf16(vf, bp, o[nt], 0, 0, 0);
                }
            }
        }
    }

    // ---- epilogue: combine partner l, normalize, write fp16 [B,L,E] ----
    const float l_tot = l_i + __shfl_xor(l_i, 32, 64);
    const float inv = 1.f / l_tot;
    const size_t rowbase = ((size_t)(b * L + q)) * E + hd * HD;
#pragma unroll
    for (int nt = 0; nt < 2; ++nt)
#pragma unroll
        for (int rr = 0; rr < 4; ++rr) {
            const int d0 = 32 * nt + 8 * rr + 4 * h;
            ushort h0 = f2h(o[nt][4 * rr + 0] * inv);
            ushort h1 = f2h(o[nt][4 * rr + 1] * inv);
            ushort h2 = f2h(o[nt][4 * rr + 2] * inv);
            ushort h3 = f2h(o[nt][4 * rr + 3] * inv);
            uint2 hw;
            hw.x = (uint)h0 | ((uint)h1 << 16);
            hw.y = (uint)h2 | ((uint)h3 << 16);
            *(uint2*)&attn16[rowbase + d0] = hw;
        }
}

extern "C" void kernel_launch(void* const* d_in, const int* in_sizes, int n_in,
                              void* d_out, int out_size, void* d_ws, size_t ws_size,
                              hipStream_t stream) {
    const float* x    = (const float*)d_in[0];
    const float* cosT = (const float*)d_in[1];
    const float* sinT = (const float*)d_in[2];
    const float* Wqkv = (const float*)d_in[3];
    const float* bqkv = (const float*)d_in[4];
    const float* Wout = (const float*)d_in[5];
    const float* bout = (const float*)d_in[6];
    float* out = (float*)d_out;

    const size_t NX = (size_t)MROWS * E;
    ushort* us   = (ushort*)d_ws;
    ushort* qh   = us;                        // [B,H,L,HD] roped+scaled q (bf16, swz)
    ushort* kh   = us + NX;                   // [B,H,L,HD] roped k (bf16, swz)
    ushort* vTp  = us + 2 * NX;               // [B,H,HD,L] v^T (bf16, sigma+swz)
    ushort* x16  = us + 3 * NX;               // x fp16
    ushort* at16 = us + 4 * NX;               // attn fp16
    ushort* wq16 = us + 5 * NX;               // Wqkv fp16
    ushort* wo16 = wq16 + (size_t)E3 * E;     // Wout fp16

    const int cvt_blocks = (int)((N1Q + N2Q + N3Q + 255) / 256);
    cvt_all<<<cvt_blocks, 256, 0, stream>>>(x, Wqkv, Wout, x16, wq16, wo16);

    gemm_f16<1><<<dim3(E3 / 128, MROWS / 128), 256, 0, stream>>>(
        x16, wq16, bqkv, nullptr, qh, kh, vTp, cosT, sinT, E3, E);

    flash_mfma4<<<dim3(B * H, L / 128), 256, 0, stream>>>(qh, kh, vTp, at16);

    gemm_f16<2><<<dim3(E / 128, MROWS / 128), 256, 0, stream>>>(
        at16, wo16, bout, out, nullptr, nullptr, nullptr, nullptr, nullptr, E, E);
}

// Round 8
// 287.755 us; speedup vs baseline: 9.1542x; 1.0006x over previous
//
#include <hip/hip_runtime.h>
#include <math.h>

#define B 4
#define L 2048
#define E 1024
#define H 16
#define HD 64
#define MROWS (B*L)      // 8192
#define E3 (3*E)         // 3072

using bf16x8   = __attribute__((ext_vector_type(8))) short;
using f16x8    = __attribute__((ext_vector_type(8))) _Float16;
using floatx4  = __attribute__((ext_vector_type(4))) float;
using floatx16 = __attribute__((ext_vector_type(16))) float;

__device__ inline ushort f2bf(float x) {
    uint u = __float_as_uint(x);
    u += 0x7FFF + ((u >> 16) & 1);     // RNE
    return (ushort)(u >> 16);
}
__device__ inline float bf2f(ushort h) { return __uint_as_float(((uint)h) << 16); }
__device__ inline ushort f2h(float x) { _Float16 h = (_Float16)x; return *(ushort*)&h; }

#if __has_builtin(__builtin_amdgcn_exp2f)
#define EXP2F(x) __builtin_amdgcn_exp2f(x)
#else
#define EXP2F(x) exp2f(x)
#endif

__device__ inline void async16(const void* g, void* l) {
    __builtin_amdgcn_global_load_lds(
        (const __attribute__((address_space(1))) uint*)g,
        (__attribute__((address_space(3))) uint*)l, 16, 0, 0);
}

// pack two fp32 -> {bf16(odd),bf16(even)} with RTZ in one v_perm
__device__ inline uint pack_rtz(float odd, float even) {
    return __builtin_amdgcn_perm(__float_as_uint(odd), __float_as_uint(even), 0x07060302u);
}

// ------------------------------------------------------------------
// fused fp32 -> fp16 convert of x | Wqkv | Wout (one launch)
// ------------------------------------------------------------------
#define N1Q ((size_t)MROWS * E / 4)        // x quads
#define N2Q ((size_t)E3 * E / 4)           // Wqkv quads
#define N3Q ((size_t)E * E / 4)            // Wout quads
__global__ __launch_bounds__(256) void cvt_all(
        const float* __restrict__ x, const float* __restrict__ wq,
        const float* __restrict__ wo, ushort* __restrict__ x16,
        ushort* __restrict__ wq16, ushort* __restrict__ wo16)
{
    size_t i = (size_t)blockIdx.x * 256 + threadIdx.x;
    const float* src; ushort* dst; size_t j;
    if (i < N1Q)                  { src = x;  dst = x16;  j = i; }
    else if (i < N1Q + N2Q)       { src = wq; dst = wq16; j = i - N1Q; }
    else                          { src = wo; dst = wo16; j = i - N1Q - N2Q; }
    float4 v = ((const float4*)src)[j];
    ushort4 o;
    o.x = f2h(v.x); o.y = f2h(v.y); o.z = f2h(v.z); o.w = f2h(v.w);
    ((ushort4*)dst)[j] = o;
}

// ------------------------------------------------------------------
// Single-pass fp16 MFMA GEMM, async double-buffered K-loop (flash-v4
// pattern: one barrier/iter, prefetch issued post-barrier). 128x128
// tile, BK=32, 256 thr = 4 waves of 64x64.
// MODE 1 epilogue: bias + RoPE (q also * 0.125*log2e); writes
//   q,k [B,H,L,HD] bf16 with 8-elem d-groups XOR-swizzled by (l&7),
//   v [B,H,HD,L] bf16 with kpos bits2,3 swapped (PV frag order) and
//   kpos-groups XOR-swizzled by (d&7).
// MODE 2 epilogue: bias, fp32 row-major out.
// ------------------------------------------------------------------
template<int MODE>
__global__ __launch_bounds__(256) void gemm_f16(
        const ushort* __restrict__ A16, const ushort* __restrict__ B16,
        const float* __restrict__ bias, float* __restrict__ Cf,
        ushort* __restrict__ qh, ushort* __restrict__ kh, ushort* __restrict__ vT,
        const float* __restrict__ cosT, const float* __restrict__ sinT,
        int Ndim, int Kdim)
{
    __shared__ ushort lds[2][8192];   // dbuf of (A tile | B tile)

    const int tid = threadIdx.x;
    const int w = tid >> 6, lane = tid & 63;
    const int g = lane >> 4, c = lane & 15;
    const int m0 = blockIdx.y * 128, n0 = blockIdx.x * 128;
    const int wm = w & 1, wn = w >> 1;

    const int rl0 = lane >> 2;
    const int jsw = (lane & 3) ^ ((lane >> 3) & 3);
    const ushort* gbase = (w < 2) ? A16 + (size_t)(m0 + 64 * (w & 1)) * Kdim
                                  : B16 + (size_t)(n0 + 64 * (w & 1)) * Kdim;
    const ushort* lanesrc = gbase + (size_t)rl0 * Kdim + jsw * 8;
    const int ldoff = (w >> 1) * 4096 + (w & 1) * 2048;

    floatx4 acc[4][4];
#pragma unroll
    for (int a = 0; a < 4; ++a)
#pragma unroll
        for (int bq = 0; bq < 4; ++bq) acc[a][bq] = (floatx4){0.f, 0.f, 0.f, 0.f};

    const int swz  = (g ^ ((c >> 1) & 3)) * 8;
    const int arow = wm * 2048 + c * 32;
    const int brow = 4096 + wn * 2048 + c * 32;

    // prologue: stage k-tile 0 into buf 0
#pragma unroll
    for (int p = 0; p < 4; ++p)
        async16(lanesrc + (size_t)p * 16 * Kdim, &lds[0][ldoff + p * 512]);

    const int NK = Kdim >> 5;   // 32
    for (int kk = 0; kk < NK; ++kk) {
        const int pb = kk & 1;
        __syncthreads();   // drains the loads targeting buf pb; syncs waves

        // prefetch k-tile kk+1 into the other buffer (flies during compute)
        if (kk + 1 < NK) {
            const ushort* ns = lanesrc + (size_t)(kk + 1) * 32;
#pragma unroll
            for (int p = 0; p < 4; ++p)
                async16(ns + (size_t)p * 16 * Kdim, &lds[pb ^ 1][ldoff + p * 512]);
        }

        const ushort* cur = &lds[pb][0];
        f16x8 af[4], bf[4];
#pragma unroll
        for (int t = 0; t < 4; ++t) {
            af[t] = *(const f16x8*)&cur[arow + t * 512 + swz];
            bf[t] = *(const f16x8*)&cur[brow + t * 512 + swz];
        }
#pragma unroll
        for (int mt = 0; mt < 4; ++mt)
#pragma unroll
            for (int nt = 0; nt < 4; ++nt)
                acc[mt][nt] = __builtin_amdgcn_mfma_f32_16x16x32_f16(af[mt], bf[nt], acc[mt][nt], 0, 0, 0);
    }

    // ---- epilogue; C/D: row = g*4+i, col = c (per 16x16 tile) ----
    const int colbase = n0 + wn * 64;
#pragma unroll
    for (int mt = 0; mt < 4; ++mt) {
        const int rowb = m0 + wm * 64 + mt * 16 + g * 4;
        if constexpr (MODE == 2) {
#pragma unroll
            for (int i = 0; i < 4; ++i) {
                const int row = rowb + i;
#pragma unroll
                for (int nt = 0; nt < 4; ++nt) {
                    const int col = colbase + nt * 16 + c;
                    Cf[(size_t)row * Ndim + col] = acc[mt][nt][i] + bias[col];
                }
            }
        } else {
            const int sec = colbase >> 10;             // 0=q 1=k 2=v
            const int hg  = (colbase & 1023) >> 6;
#pragma unroll
            for (int i = 0; i < 4; ++i) {
                const int row = rowb + i;
                const int bb = row >> 11;
                const int l  = row & (L - 1);
                if (sec < 2) {
                    ushort* dst = (sec == 0 ? qh : kh) + ((size_t)(bb * H + hg) * L + l) * HD;
                    const int sw = l & 7;
                    // q carries softmax scale AND log2e for the exp2 softmax
                    const float qs = (sec == 0) ? 0.18033688f : 1.0f;
#pragma unroll
                    for (int nt = 0; nt < 2; ++nt) {
                        const int d  = nt * 16 + c;
                        const int d2 = d + 32;
                        float v1 = acc[mt][nt][i]     + bias[colbase + d];
                        float v2 = acc[mt][nt + 2][i] + bias[colbase + d2];
                        float cs = cosT[l * 32 + d], sn = sinT[l * 32 + d];
                        dst[(((d  >> 3) ^ sw) << 3) | (d  & 7)] = f2bf((v1 * cs - v2 * sn) * qs);
                        dst[(((d2 >> 3) ^ sw) << 3) | (d2 & 7)] = f2bf((v1 * sn + v2 * cs) * qs);
                    }
                } else {
                    // sigma: swap bits 2,3 of kpos; then group-swizzle by d&7
                    const int lp = (l & ~12) | ((l & 4) << 1) | ((l & 8) >> 1);
                    const int intile = ((((lp >> 3) & 7)) << 3);
#pragma unroll
                    for (int nt = 0; nt < 4; ++nt) {
                        const int d = nt * 16 + c;
                        float v = acc[mt][nt][i] + bias[colbase + d];
                        size_t idx = ((size_t)(bb * H + hg) * HD + d) * L
                                   + (l & ~63) + (intile ^ ((d & 7) << 3)) + (lp & 7);
                        vT[idx] = f2bf(v);
                    }
                }
            }
        }
    }
}

// ------------------------------------------------------------------
// Flash attention v4 (unchanged from R7): fixed-shift streaming softmax,
// sigma-ordered V (P packs straight from MFMA regs), async double-
// buffered global_load_lds staging, swizzled layouts.
// ------------------------------------------------------------------
__global__ __launch_bounds__(256, 4) void flash_mfma4(
        const ushort* __restrict__ qh, const ushort* __restrict__ kh,
        const ushort* __restrict__ vT, ushort* __restrict__ attn16)
{
    __shared__ ushort Ks[2][4096];
    __shared__ ushort Vt[2][4096];

    const int tid  = threadIdx.x;
    const int w    = tid >> 6;
    const int lane = tid & 63;
    const int h    = lane >> 5;
    const int n    = lane & 31;
    const int b    = blockIdx.x >> 4;
    const int hd   = blockIdx.x & 15;
    const int q0   = blockIdx.y * 128;

    const ushort* khead = kh + (size_t)(b * H + hd) * L * HD;
    const ushort* vhead = vT + (size_t)(b * H + hd) * HD * L;

    const int q = q0 + 32 * w + n;
    const ushort* qrow = qh + ((size_t)(b * H + hd) * L + q) * HD;
    bf16x8 aq[4];
#pragma unroll
    for (int kd = 0; kd < 4; ++kd)
        aq[kd] = *(const bf16x8*)&qrow[((2 * kd + h) ^ (q & 7)) << 3];

    const int wk = w & 1;
    const ushort* ksrc = khead + (size_t)(32 * wk) * 64 + lane * 8;
    const ushort* vsrc = vhead + (size_t)(32 * wk + (lane >> 3)) * L + (lane & 7) * 8;

    const int NIT = L / 64;   // 32
    if (w < 2) {
#pragma unroll
        for (int p = 0; p < 4; ++p)
            async16(ksrc + p * 512, &Ks[0][32 * wk * 64 + p * 512]);
    } else {
#pragma unroll
        for (int p = 0; p < 4; ++p)
            async16(vsrc + (size_t)p * 8 * L, &Vt[0][32 * wk * 64 + p * 512]);
    }

    float l_i = 0.f;
    floatx16 o[2];
    o[0] = (floatx16)(0.f);
    o[1] = (floatx16)(0.f);

    for (int it = 0; it < NIT; ++it) {
        const int p = it & 1;
        __syncthreads();

        if (it + 1 < NIT) {
            if (w < 2) {
                const ushort* s = ksrc + (size_t)(it + 1) * 4096;
#pragma unroll
                for (int pp = 0; pp < 4; ++pp)
                    async16(s + pp * 512, &Ks[p ^ 1][32 * wk * 64 + pp * 512]);
            } else {
                const ushort* s = vsrc + (size_t)(it + 1) * 64;
#pragma unroll
                for (int pp = 0; pp < 4; ++pp)
                    async16(s + (size_t)pp * 8 * L, &Vt[p ^ 1][32 * wk * 64 + pp * 512]);
            }
        }

        const ushort* KsC = Ks[p];
        const ushort* VtC = Vt[p];

#pragma unroll
        for (int js = 0; js < 2; ++js) {
            floatx16 s = (floatx16)(-16.0f);
#pragma unroll
            for (int kd = 0; kd < 4; ++kd) {
                bf16x8 kf = *(const bf16x8*)&KsC[(32 * js + n) * 64 + (((2 * kd + h) ^ (n & 7)) << 3)];
                s = __builtin_amdgcn_mfma_f32_32x32x16_bf16(kf, aq[kd], s, 0, 0, 0);
            }

            float pv[16];
            float rs = 0.f;
#pragma unroll
            for (int rr = 0; rr < 4; ++rr) {
                float p0 = EXP2F(s[4 * rr + 0]);
                float p1 = EXP2F(s[4 * rr + 1]);
                float p2 = EXP2F(s[4 * rr + 2]);
                float p3 = EXP2F(s[4 * rr + 3]);
                pv[4 * rr + 0] = p0; pv[4 * rr + 1] = p1;
                pv[4 * rr + 2] = p2; pv[4 * rr + 3] = p3;
                rs += (p0 + p1) + (p2 + p3);
            }
            l_i += rs;

#pragma unroll
            for (int f = 0; f < 2; ++f) {
                uint bu[4];
                bu[0] = pack_rtz(pv[8 * f + 1], pv[8 * f + 0]);
                bu[1] = pack_rtz(pv[8 * f + 3], pv[8 * f + 2]);
                bu[2] = pack_rtz(pv[8 * f + 5], pv[8 * f + 4]);
                bu[3] = pack_rtz(pv[8 * f + 7], pv[8 * f + 6]);
                bf16x8 bp = *(const bf16x8*)&bu[0];
#pragma unroll
                for (int nt = 0; nt < 2; ++nt) {
                    bf16x8 vf = *(const bf16x8*)&VtC[(32 * nt + n) * 64 + (((4 * js + 2 * f + h) ^ (n & 7)) << 3)];
                    o[nt] = __builtin_amdgcn_mfma_f32_32x32x16_bf16(vf, bp, o[nt], 0, 0, 0);
                }
            }
        }
    }

    const float l_tot = l_i + __shfl_xor(l_i, 32, 64);
    const float inv = 1.f / l_tot;
    const size_t rowbase = ((size_t)(b * L + q)) * E + hd * HD;
#pragma unroll
    for (int nt = 0; nt < 2; ++nt)
#pragma unroll
        for (int rr = 0; rr < 4; ++rr) {
            const int d0 = 32 * nt + 8 * rr + 4 * h;
            ushort h0 = f2h(o[nt][4 * rr + 0] * inv);
            ushort h1 = f2h(o[nt][4 * rr + 1] * inv);
            ushort h2 = f2h(o[nt][4 * rr + 2] * inv);
            ushort h3 = f2h(o[nt][4 * rr + 3] * inv);
            uint2 hw;
            hw.x = (uint)h0 | ((uint)h1 << 16);
            hw.y = (uint)h2 | ((uint)h3 << 16);
            *(uint2*)&attn16[rowbase + d0] = hw;
        }
}

extern "C" void kernel_launch(void* const* d_in, const int* in_sizes, int n_in,
                              void* d_out, int out_size, void* d_ws, size_t ws_size,
                              hipStream_t stream) {
    const float* x    = (const float*)d_in[0];
    const float* cosT = (const float*)d_in[1];
    const float* sinT = (const float*)d_in[2];
    const float* Wqkv = (const float*)d_in[3];
    const float* bqkv = (const float*)d_in[4];
    const float* Wout = (const float*)d_in[5];
    const float* bout = (const float*)d_in[6];
    float* out = (float*)d_out;

    const size_t NX = (size_t)MROWS * E;
    ushort* us   = (ushort*)d_ws;
    ushort* qh   = us;                        // [B,H,L,HD] roped+scaled q (bf16, swz)
    ushort* kh   = us + NX;                   // [B,H,L,HD] roped k (bf16, swz)
    ushort* vTp  = us + 2 * NX;               // [B,H,HD,L] v^T (bf16, sigma+swz)
    ushort* x16  = us + 3 * NX;               // x fp16
    ushort* at16 = us + 4 * NX;               // attn fp16
    ushort* wq16 = us + 5 * NX;               // Wqkv fp16
    ushort* wo16 = wq16 + (size_t)E3 * E;     // Wout fp16

    const int cvt_blocks = (int)((N1Q + N2Q + N3Q + 255) / 256);
    cvt_all<<<cvt_blocks, 256, 0, stream>>>(x, Wqkv, Wout, x16, wq16, wo16);

    gemm_f16<1><<<dim3(E3 / 128, MROWS / 128), 256, 0, stream>>>(
        x16, wq16, bqkv, nullptr, qh, kh, vTp, cosT, sinT, E3, E);

    flash_mfma4<<<dim3(B * H, L / 128), 256, 0, stream>>>(qh, kh, vTp, at16);

    gemm_f16<2><<<dim3(E / 128, MROWS / 128), 256, 0, stream>>>(
        at16, wo16, bout, out, nullptr, nullptr, nullptr, nullptr, nullptr, E, E);
}